// Round 13
// baseline (471.272 us; speedup 1.0000x reference)
//
#include <hip/hip_runtime.h>
#include <math.h>

typedef __attribute__((ext_vector_type(8))) short short8;
typedef __attribute__((ext_vector_type(4))) float f32x4;

#define BB 2
#define NN 2048
#define KK 32
#define HH 128
#define DFF 512
#define EPSF 1e-6f
#define INFV 1e30f

#define MFMA16(a, b, c) __builtin_amdgcn_mfma_f32_16x16x32_bf16((a), (b), (c), 0, 0, 0)

// ---------- helpers ----------

__device__ __forceinline__ unsigned short f2bf(float f) {
    unsigned u = __float_as_uint(f);
    u += 0x7fffu + ((u >> 16) & 1u);          // round-to-nearest-even
    return (unsigned short)(u >> 16);
}

__device__ __forceinline__ float bf2f(unsigned short h) {
    return __uint_as_float(((unsigned)h) << 16);
}

// split x into hi+lo bf16 pair — WEIGHTS only (systematic error must stay split)
__device__ __forceinline__ void f2bf2(float x, short& hi, short& lo) {
    unsigned short h = f2bf(x);
    hi = (short)h;
    lo = (short)f2bf(x - bf2f(h));
}

// pack 8 floats -> hi-plane short8
__device__ __forceinline__ short8 cvt8h(f32x4 a, f32x4 b) {
    short8 h8;
    #pragma unroll
    for (int i = 0; i < 4; i++) h8[i] = (short)f2bf(a[i]);
    #pragma unroll
    for (int i = 0; i < 4; i++) h8[4 + i] = (short)f2bf(b[i]);
    return h8;
}

__device__ __forceinline__ float sgnf(float x) {
    return (x > 0.f) ? 1.f : ((x < 0.f) ? -1.f : 0.f);
}

__device__ __forceinline__ void norm3(float& x, float& y, float& z) {
    float n = sqrtf(x * x + y * y + z * z);
    n = fmaxf(n, 1e-12f);
    x /= n; y /= n; z /= n;
}

// block of 128 threads: sum over all threads, broadcast. 2 barriers.
__device__ __forceinline__ float blk2sum(float v, float* slots) {
    int lane = threadIdx.x & 63, wid = threadIdx.x >> 6;
    #pragma unroll
    for (int off = 32; off > 0; off >>= 1) v += __shfl_down(v, off);
    if (lane == 0) slots[wid] = v;
    __syncthreads();
    float r = slots[0] + slots[1];
    __syncthreads();
    return r;
}

// LN stats over 128 cols held in C-fragment layout (8 nt x f32x4)
__device__ __forceinline__ void lnC(const f32x4* vC, float* mu, float* inv) {
    float su[4] = {0, 0, 0, 0}, sq[4] = {0, 0, 0, 0};
    #pragma unroll
    for (int nt = 0; nt < 8; nt++)
        #pragma unroll
        for (int r = 0; r < 4; r++) { float v = vC[nt][r]; su[r] += v; sq[r] += v * v; }
    #pragma unroll
    for (int off = 1; off <= 8; off <<= 1)
        #pragma unroll
        for (int r = 0; r < 4; r++) { su[r] += __shfl_xor(su[r], off); sq[r] += __shfl_xor(sq[r], off); }
    #pragma unroll
    for (int r = 0; r < 4; r++) {
        mu[r] = su[r] * (1.f / HH);
        float var = (sq[r] - (float)HH * mu[r] * mu[r]) * (1.f / (HH - 1));
        inv[r] = 1.f / (sqrtf(var + EPSF) + EPSF);
    }
}

// ---------- kNN v5: 4 independent waves per block, ballot fast-path tiebreak ----------

__global__ __launch_bounds__(256) void knn_kernel(const float* __restrict__ X,
                                                  const float* __restrict__ mask,
                                                  int* __restrict__ E_idx,
                                                  float* __restrict__ D_nb) {
    int w = threadIdx.x >> 6, lane = threadIdx.x & 63;
    int g = blockIdx.x * 4 + w;
    int b = g >> 11, n = g & 2047;
    const float* Xb = X + (size_t)b * NN * 3;
    const float* mb = mask + (size_t)b * NN;

    float xn0 = Xb[n * 3], xn1 = Xb[n * 3 + 1], xn2 = Xb[n * 3 + 2];
    float mn = mb[n];

    float Dv[32], m2a[32];
    float lmax = -1e30f;
    #pragma unroll
    for (int s = 0; s < 32; s++) {
        int j = s * 64 + lane;
        float dx = Xb[j * 3] - xn0, dy = Xb[j * 3 + 1] - xn1, dz = Xb[j * 3 + 2] - xn2;
        float d = sqrtf(dx * dx + dy * dy + dz * dz + EPSF);
        float m2 = mn * mb[j];
        float v = m2 * d;
        Dv[s] = v; m2a[s] = m2;
        lmax = fmaxf(lmax, v);
    }
    #pragma unroll
    for (int off = 1; off <= 32; off <<= 1) lmax = fmaxf(lmax, __shfl_xor(lmax, off));
    float Dmax = lmax;
    #pragma unroll
    for (int s = 0; s < 32; s++) Dv[s] += (1.f - m2a[s]) * Dmax;

    // per-lane top-2 (strict < keeps earliest slot on exact ties)
    float l1 = INFV, l2 = INFV; int s1 = 0, s2 = 0;
    #pragma unroll
    for (int s = 0; s < 32; s++) {
        float v = Dv[s];
        bool lt1 = v < l1;
        bool lt2 = v < l2;
        float o1 = l1; int os1 = s1;
        l1 = lt1 ? v : l1;  s1 = lt1 ? s : s1;
        l2 = lt1 ? o1 : (lt2 ? v : l2);
        s2 = lt1 ? os1 : (lt2 ? s : s2);
    }

    unsigned used = 0u;
    float keepd = 0.f; int keepj = 0;

    for (int s = 0; s < KK; s++) {
        float m = l1;
        #pragma unroll
        for (int off = 1; off <= 32; off <<= 1) m = fminf(m, __shfl_xor(m, off));
        unsigned long long ball = __ballot(l1 == m);
        int jwin;
        if (__popcll(ball) == 1) {
            int src = (int)(__ffsll((long long)ball) - 1);
            jwin = __shfl(s1 * 64 + lane, src);
        } else {
            int jme = (l1 == m) ? (s1 * 64 + lane) : 0x7FFFFFFF;
            jwin = jme;
            #pragma unroll
            for (int off = 1; off <= 32; off <<= 1) jwin = min(jwin, __shfl_xor(jwin, off));
        }
        if (lane == s) { keepd = m; keepj = jwin; }
        if (lane == (jwin & 63)) {
            used |= 1u << s1;
            l1 = l2; s1 = s2;
            l2 = INFV;
            if (l1 >= INFV) {   // rare refill
                l1 = INFV; l2 = INFV;
                #pragma unroll
                for (int i = 0; i < 32; i++) {
                    float v = ((used >> i) & 1u) ? INFV : Dv[i];
                    bool lt1 = v < l1;
                    bool lt2 = v < l2;
                    float o1 = l1; int os1 = s1;
                    l1 = lt1 ? v : l1;  s1 = lt1 ? i : s1;
                    l2 = lt1 ? o1 : (lt2 ? v : l2);
                    s2 = lt1 ? os1 : (lt2 ? i : s2);
                }
            }
        }
    }
    if (lane < KK) {
        E_idx[(size_t)g * KK + lane] = keepj;
        D_nb[(size_t)g * KK + lane] = keepd;
    }
}

// ---------- weight pre-pack: fp32 -> (hi,lo) bf16 B-fragment planes ----------

__device__ __forceinline__ void packB(const float* __restrict__ src, short* __restrict__ dH,
                                      short* __restrict__ dL, int e, int KC, int N, int Kreal) {
    int j = e & 7, ln = (e >> 3) & 63, t = e >> 9;
    int kc = t % KC, nt = t / KC;
    int k = kc * 32 + (ln >> 4) * 8 + j;
    int n = nt * 16 + (ln & 15);
    float v = (k < Kreal) ? src[(size_t)k * N + n] : 0.f;
    short hi, lo; f2bf2(v, hi, lo);
    dH[e] = hi; dL[e] = lo;
}

__global__ __launch_bounds__(256) void pack_kernel(const float* __restrict__ We,
                                                   const float* __restrict__ Wq,
                                                   const float* __restrict__ lW1,
                                                   const float* __restrict__ lW2,
                                                   const float* __restrict__ lW3,
                                                   const float* __restrict__ lWi,
                                                   const float* __restrict__ lWo,
                                                   short* __restrict__ WeP,
                                                   short* __restrict__ WqP,
                                                   short* __restrict__ W1bP,
                                                   short* __restrict__ W2P,
                                                   short* __restrict__ W3P,
                                                   short* __restrict__ WiP,
                                                   short* __restrict__ WoP,
                                                   short* __restrict__ W1acP) {
    int e = blockIdx.x * 256 + threadIdx.x;
    if (e < 8192) { packB(We, WeP, WeP + 8192, e, 2, 128, 39); return; }
    e -= 8192;
    if (e < 16384) { packB(Wq, WqP, WqP + 16384, e, 4, 128, 128); return; }
    e -= 16384;
    if (e < 49152) {
        int l = e >> 14, r = e & 16383;
        packB(lW1 + (size_t)l * 49152 + 16384, W1bP + l * 32768, W1bP + l * 32768 + 16384, r, 4, 128, 128);
        return;
    }
    e -= 49152;
    if (e < 49152) {
        int l = e >> 14, r = e & 16383;
        packB(lW2 + (size_t)l * 16384, W2P + l * 32768, W2P + l * 32768 + 16384, r, 4, 128, 128);
        return;
    }
    e -= 49152;
    if (e < 49152) {
        int l = e >> 14, r = e & 16383;
        packB(lW3 + (size_t)l * 16384, W3P + l * 32768, W3P + l * 32768 + 16384, r, 4, 128, 128);
        return;
    }
    e -= 49152;
    if (e < 196608) {
        int l = e / 65536, r = e % 65536;
        packB(lWi + (size_t)l * 65536, WiP + l * 131072, WiP + l * 131072 + 65536, r, 4, 512, 128);
        return;
    }
    e -= 196608;
    if (e < 196608) {
        int l = e / 65536, r = e % 65536;
        packB(lWo + (size_t)l * 65536, WoP + l * 131072, WoP + l * 131072 + 65536, r, 16, 128, 512);
        return;
    }
    e -= 196608;
    if (e < 98304) {
        int l = e / 32768, r = e % 32768;
        int j = r & 7, ln = (r >> 3) & 63, t = r >> 9;
        int kc = t & 3, nt = t >> 2;
        int k = kc * 32 + (ln >> 4) * 8 + j;
        int n = nt * 16 + (ln & 15);
        const float* base = lW1 + (size_t)l * 49152;
        float v = (n < 128) ? base[(size_t)k * 128 + n] : base[(size_t)(256 + k) * 128 + (n - 128)];
        short hi, lo; f2bf2(v, hi, lo);
        short* dH = W1acP + l * 65536;
        dH[r] = hi; dH[32768 + r] = lo;
    }
}

// ---------- backbone frames ----------

__global__ void orient_kernel(const float* __restrict__ X,
                              float* __restrict__ AD,
                              float* __restrict__ Of) {
    int t = blockIdx.x * blockDim.x + threadIdx.x;
    if (t >= BB * NN) return;
    int b = t / NN, n = t % NN;
    float* ad = AD + (size_t)t * 3;
    float* of = Of + (size_t)t * 9;
    if (n < 1 || n > NN - 3) {
        ad[0] = ad[1] = ad[2] = 0.f;
        #pragma unroll
        for (int i = 0; i < 9; i++) of[i] = 0.f;
        return;
    }
    const float* Xb = X + (size_t)b * NN * 3;
    float p0x = Xb[(n - 1) * 3], p0y = Xb[(n - 1) * 3 + 1], p0z = Xb[(n - 1) * 3 + 2];
    float p1x = Xb[n * 3],       p1y = Xb[n * 3 + 1],       p1z = Xb[n * 3 + 2];
    float p2x = Xb[(n + 1) * 3], p2y = Xb[(n + 1) * 3 + 1], p2z = Xb[(n + 1) * 3 + 2];
    float p3x = Xb[(n + 2) * 3], p3y = Xb[(n + 2) * 3 + 1], p3z = Xb[(n + 2) * 3 + 2];

    float u2x = p1x - p0x, u2y = p1y - p0y, u2z = p1z - p0z; norm3(u2x, u2y, u2z);
    float u1x = p2x - p1x, u1y = p2y - p1y, u1z = p2z - p1z; norm3(u1x, u1y, u1z);
    float u0x = p3x - p2x, u0y = p3y - p2y, u0z = p3z - p2z; norm3(u0x, u0y, u0z);

    float n2x = u2y * u1z - u2z * u1y, n2y = u2z * u1x - u2x * u1z, n2z = u2x * u1y - u2y * u1x;
    norm3(n2x, n2y, n2z);
    float n1x = u1y * u0z - u1z * u0y, n1y = u1z * u0x - u1x * u0z, n1z = u1x * u0y - u1y * u0x;
    norm3(n1x, n1y, n1z);

    float cosA = -(u1x * u0x + u1y * u0y + u1z * u0z);
    cosA = fminf(fmaxf(cosA, -1.f + EPSF), 1.f - EPSF);
    float A = acosf(cosA);
    float cosD = n2x * n1x + n2y * n1y + n2z * n1z;
    cosD = fminf(fmaxf(cosD, -1.f + EPSF), 1.f - EPSF);
    float sg = sgnf(u2x * n1x + u2y * n1y + u2z * n1z);
    float Dih = sg * acosf(cosD);

    ad[0] = cosf(A);
    ad[1] = sinf(A) * cosf(Dih);
    ad[2] = sinf(A) * sinf(Dih);

    float o1x = u2x - u1x, o1y = u2y - u1y, o1z = u2z - u1z; norm3(o1x, o1y, o1z);
    float cx = o1y * n2z - o1z * n2y, cy = o1z * n2x - o1x * n2z, cz = o1x * n2y - o1y * n2x;
    of[0] = o1x; of[1] = o1y; of[2] = o1z;
    of[3] = n2x; of[4] = n2y; of[5] = n2z;
    of[6] = cx;  of[7] = cy;  of[8] = cz;
}

// ---------- node features + premix for layer 0 (fp32) ----------

__global__ __launch_bounds__(128) void node_feat_kernel(const float* __restrict__ AD,
                                                        const float* __restrict__ Wn,
                                                        const float* __restrict__ bn,
                                                        const float* __restrict__ gn,
                                                        const float* __restrict__ hn,
                                                        const float* __restrict__ Wv,
                                                        const float* __restrict__ bv,
                                                        const float* __restrict__ W1_0,
                                                        const float* __restrict__ b1_0,
                                                        float* __restrict__ hV,
                                                        float* __restrict__ P,
                                                        float* __restrict__ Q) {
    __shared__ __align__(16) float y[HH];
    __shared__ float slots[2];
    int n = blockIdx.x; int h = threadIdx.x;
    float a0 = AD[n * 3], a1 = AD[n * 3 + 1], a2 = AD[n * 3 + 2];
    float v = bn[h] + a0 * Wn[h] + a1 * Wn[HH + h] + a2 * Wn[2 * HH + h];
    float mu = blk2sum(v, slots) * (1.f / HH);
    float d = v - mu;
    float var = blk2sum(d * d, slots) * (1.f / (HH - 1));
    float yv = gn[h] * d / (sqrtf(var + EPSF) + EPSF) + hn[h];
    y[h] = yv; __syncthreads();
    float acc = bv[h];
    for (int c4 = 0; c4 < 32; c4++) {
        f32x4 v4 = ((const f32x4*)y)[c4]; int c = 4 * c4;
        acc += v4.x * Wv[c * HH + h] + v4.y * Wv[(c + 1) * HH + h]
             + v4.z * Wv[(c + 2) * HH + h] + v4.w * Wv[(c + 3) * HH + h];
    }
    hV[(size_t)n * HH + h] = acc;
    __syncthreads(); y[h] = acc; __syncthreads();
    float p = b1_0[h], qv = 0.f;
    for (int c4 = 0; c4 < 32; c4++) {
        f32x4 v4 = ((const f32x4*)y)[c4]; int c = 4 * c4;
        p  += v4.x * W1_0[c * HH + h]        + v4.y * W1_0[(c + 1) * HH + h]
            + v4.z * W1_0[(c + 2) * HH + h]  + v4.w * W1_0[(c + 3) * HH + h];
        qv += v4.x * W1_0[(256 + c) * HH + h]       + v4.y * W1_0[(256 + c + 1) * HH + h]
            + v4.z * W1_0[(256 + c + 2) * HH + h]   + v4.w * W1_0[(256 + c + 3) * HH + h];
    }
    P[(size_t)n * HH + h] = p;
    Q[(size_t)n * HH + h] = qv;
}

// ---------- edge features + FUSED layer-0 message pass ----------
// After computing h_E (C-frags), reuse it in-kernel for layer 0's
// m1 = relu(P + Q[nbr] + h_E@W1b0), m2 = relu(m1@W2_0+b2_0), masked K-sum.
// Writes hEbH (for layers 1,2) + sOut/cntOut (layer 0).

__global__ __launch_bounds__(128) void edge_feat_kernel(const float* __restrict__ X,
                                                        const int* __restrict__ E_idx,
                                                        const float* __restrict__ D_nb,
                                                        const float* __restrict__ Of,
                                                        const float* __restrict__ be,
                                                        const float* __restrict__ ge,
                                                        const float* __restrict__ he,
                                                        const float* __restrict__ bq,
                                                        const short* __restrict__ WeP,
                                                        const short* __restrict__ WqP,
                                                        const float* __restrict__ mask,
                                                        const float* __restrict__ P,
                                                        const float* __restrict__ Q,
                                                        const short* __restrict__ W1bP0,
                                                        const short* __restrict__ W2P0,
                                                        const float* __restrict__ b2v,
                                                        unsigned short* __restrict__ hEbH,
                                                        float* __restrict__ sOut,
                                                        float* __restrict__ cntOut) {
    __shared__ short AefH[32 * 72];
    __shared__ short AeH[32 * 136];
    __shared__ float beS[HH], geS[HH], heS[HH], bqS[HH];
    __shared__ __align__(16) float s2[256];
    __shared__ float mattS[KK];
    __shared__ int eixS[KK];

    int bid = blockIdx.x; int b = bid >> 11, n = bid & 2047; int tid = threadIdx.x;
    int lane = tid & 63, w = tid >> 6;
    beS[tid] = be[tid]; geS[tid] = ge[tid]; heS[tid] = he[tid]; bqS[tid] = bq[tid];
    {
        unsigned* Az = (unsigned*)AefH;
        for (int i = tid; i < 32 * 72 / 2; i += 128) Az[i] = 0u;
    }
    float maskv = mask[bid];

    int part = tid >> 5, k = tid & 31;
    int e = E_idx[(size_t)bid * KK + k];
    if (part == 0) {
        eixS[k] = e;
        mattS[k] = maskv * mask[b * NN + e];
    }
    float dpos = (float)e - (float)n;
    if (part == 1 || part == 2) {
        int p0 = (part - 1) * 4;
        #pragma unroll
        for (int p = 0; p < 4; p++) {
            float fr = expf((float)(2 * (p0 + p)) * -0.5756462732485115f);
            float ang = dpos * fr;
            AefH[k * 72 + p0 + p]     = (short)f2bf(cosf(ang));
            AefH[k * 72 + 8 + p0 + p] = (short)f2bf(sinf(ang));
        }
    } else if (part == 3) {
        float Dv = D_nb[(size_t)bid * KK + k];
        #pragma unroll
        for (int i = 0; i < 16; i++) {
            float m = (20.f / 15.f) * (float)i;
            float z = (Dv - m) * 0.8f;
            AefH[k * 72 + 16 + i] = (short)f2bf(expf(-z * z));
        }
    } else {
        const float* Omp = Of + (size_t)(b * NN + n) * 9;
        const float* Onp = Of + (size_t)(b * NN + e) * 9;
        float Om[9], On[9];
        #pragma unroll
        for (int i = 0; i < 9; i++) { Om[i] = Omp[i]; On[i] = Onp[i]; }
        float vx = X[(size_t)(b * NN + e) * 3 + 0] - X[(size_t)(b * NN + n) * 3 + 0];
        float vy = X[(size_t)(b * NN + e) * 3 + 1] - X[(size_t)(b * NN + n) * 3 + 1];
        float vz = X[(size_t)(b * NN + e) * 3 + 2] - X[(size_t)(b * NN + n) * 3 + 2];
        float t0 = Om[0] * vx + Om[1] * vy + Om[2] * vz;
        float t1 = Om[3] * vx + Om[4] * vy + Om[5] * vz;
        float t2 = Om[6] * vx + Om[7] * vy + Om[8] * vz;
        float nr = fmaxf(sqrtf(t0 * t0 + t1 * t1 + t2 * t2), 1e-12f);
        AefH[k * 72 + 32] = (short)f2bf(t0 / nr);
        AefH[k * 72 + 33] = (short)f2bf(t1 / nr);
        AefH[k * 72 + 34] = (short)f2bf(t2 / nr);
        float R[9];
        #pragma unroll
        for (int i = 0; i < 3; i++)
            #pragma unroll
            for (int l = 0; l < 3; l++)
                R[i * 3 + l] = Om[0 + i] * On[0 + l] + Om[3 + i] * On[3 + l] + Om[6 + i] * On[6 + l];
        float Rxx = R[0], Ryy = R[4], Rzz = R[8];
        float mx = 0.5f * sqrtf(fabsf(1.f + Rxx - Ryy - Rzz));
        float my = 0.5f * sqrtf(fabsf(1.f - Rxx + Ryy - Rzz));
        float mz = 0.5f * sqrtf(fabsf(1.f - Rxx - Ryy + Rzz));
        float qx = sgnf(R[7] - R[5]) * mx;
        float qy = sgnf(R[2] - R[6]) * my;
        float qz = sgnf(R[3] - R[1]) * mz;
        float qw = 0.5f * sqrtf(fmaxf(1.f + Rxx + Ryy + Rzz, 0.f));
        float qn = fmaxf(sqrtf(qx * qx + qy * qy + qz * qz + qw * qw), 1e-12f);
        AefH[k * 72 + 35] = (short)f2bf(qx / qn);
        AefH[k * 72 + 36] = (short)f2bf(qy / qn);
        AefH[k * 72 + 37] = (short)f2bf(qz / qn);
        AefH[k * 72 + 38] = (short)f2bf(qw / qn);
    }
    __syncthreads();

    int m = lane & 15, q = lane >> 4;

    // GEMM1: feats -> E, LN, stage to AeH
    {
        int row = (w * 16 + m) * 72;
        short8 a0h = *(const short8*)&AefH[row + q * 8];
        short8 a1h = *(const short8*)&AefH[row + 32 + q * 8];
        f32x4 accA[8];
        #pragma unroll
        for (int nt = 0; nt < 8; nt++) {
            float bc = beS[nt * 16 + m];
            f32x4 acc = {bc, bc, bc, bc};
            const short* B0 = &WeP[((nt * 2 + 0) * 64 + lane) * 8];
            const short* B1 = &WeP[((nt * 2 + 1) * 64 + lane) * 8];
            short8 b0h = *(const short8*)B0, b0l = *(const short8*)(B0 + 8192);
            short8 b1h = *(const short8*)B1, b1l = *(const short8*)(B1 + 8192);
            acc = MFMA16(a0h, b0h, acc);
            acc = MFMA16(a0h, b0l, acc);
            acc = MFMA16(a1h, b1h, acc);
            acc = MFMA16(a1h, b1l, acc);
            accA[nt] = acc;
        }
        float mu[4], inv[4];
        lnC(accA, mu, inv);
        #pragma unroll
        for (int nt = 0; nt < 8; nt++) {
            int col = nt * 16 + m;
            float g = geS[col], hh = heS[col];
            #pragma unroll
            for (int r = 0; r < 4; r++) {
                int edge = w * 16 + q * 4 + r;
                float y = g * (accA[nt][r] - mu[r]) * inv[r] + hh;
                AeH[edge * 136 + col] = (short)f2bf(y);
            }
        }
    }
    __syncthreads();

    // GEMM2: E @ Wq -> h_E (C-frags); write hi to global; restage into AeH
    {
        short8 ah[4];
        #pragma unroll
        for (int kc = 0; kc < 4; kc++)
            ah[kc] = *(const short8*)&AeH[(w * 16 + m) * 136 + kc * 32 + q * 8];
        #pragma unroll
        for (int nt = 0; nt < 8; nt++) {
            int col = nt * 16 + m;
            float bc = bqS[col];
            f32x4 acc = {bc, bc, bc, bc};
            #pragma unroll
            for (int kc = 0; kc < 4; kc++) {
                const short* Bp = &WqP[((nt * 4 + kc) * 64 + lane) * 8];
                short8 bh = *(const short8*)Bp, bl = *(const short8*)(Bp + 16384);
                acc = MFMA16(ah[kc], bh, acc);
                acc = MFMA16(ah[kc], bl, acc);
            }
            #pragma unroll
            for (int r = 0; r < 4; r++) {
                int edge = w * 16 + q * 4 + r;
                unsigned short hv = f2bf(acc[r]);
                hEbH[(size_t)bid * (KK * HH) + edge * HH + col] = hv;
                AeH[edge * 136 + col] = (short)hv;   // wave-local rows; in-order DS ops
            }
        }
    }

    // ---- fused layer-0 message pass ----
    int erow[4]; float mtv[4];
    #pragma unroll
    for (int r = 0; r < 4; r++) {
        erow[r] = eixS[w * 16 + q * 4 + r];
        mtv[r]  = mattS[w * 16 + q * 4 + r];
    }
    float preg[8], b2reg[8], qreg[8][4];
    #pragma unroll
    for (int nt = 0; nt < 8; nt++) {
        preg[nt]  = P[(size_t)bid * HH + nt * 16 + m];
        b2reg[nt] = b2v[nt * 16 + m];
        #pragma unroll
        for (int r = 0; r < 4; r++)
            qreg[nt][r] = Q[((size_t)b * NN + erow[r]) * HH + nt * 16 + m];
    }

    // phase 1: m1 = relu(P + Q[nbr] + h_E @ W1b0)
    {
        short8 ahe[4];
        #pragma unroll
        for (int kc = 0; kc < 4; kc++)
            ahe[kc] = *(const short8*)&AeH[(w * 16 + m) * 136 + kc * 32 + q * 8];
        #pragma unroll
        for (int nt = 0; nt < 8; nt++) {
            f32x4 t = {0.f, 0.f, 0.f, 0.f};
            #pragma unroll
            for (int kc = 0; kc < 4; kc++) {
                const short* Bp = &W1bP0[((nt * 4 + kc) * 64 + lane) * 8];
                short8 bh = *(const short8*)Bp, bl = *(const short8*)(Bp + 16384);
                t = MFMA16(ahe[kc], bh, t);
                t = MFMA16(ahe[kc], bl, t);
            }
            int col = nt * 16 + m;
            float pp = preg[nt];
            #pragma unroll
            for (int r = 0; r < 4; r++) {
                float v = fmaxf(t[r] + pp + qreg[nt][r], 0.f);
                AeH[(w * 16 + q * 4 + r) * 136 + col] = (short)f2bf(v);
            }
        }
    }

    // phase 2: m2 = relu(m1 @ W2_0 + b2_0); masked per-wave 16-edge sum
    {
        short8 am[4];
        #pragma unroll
        for (int kc = 0; kc < 4; kc++)
            am[kc] = *(const short8*)&AeH[(w * 16 + m) * 136 + kc * 32 + q * 8];
        #pragma unroll
        for (int nt = 0; nt < 8; nt++) {
            int col = nt * 16 + m;
            float bc = b2reg[nt];
            f32x4 acc = {bc, bc, bc, bc};
            #pragma unroll
            for (int kc = 0; kc < 4; kc++) {
                const short* Bp = &W2P0[((nt * 4 + kc) * 64 + lane) * 8];
                short8 bh = *(const short8*)Bp, bl = *(const short8*)(Bp + 16384);
                acc = MFMA16(am[kc], bh, acc);
                acc = MFMA16(am[kc], bl, acc);
            }
            float pt = 0.f;
            #pragma unroll
            for (int r = 0; r < 4; r++) pt += fmaxf(acc[r], 0.f) * mtv[r];
            pt += __shfl_xor(pt, 16);
            pt += __shfl_xor(pt, 32);
            if (q == 0) s2[w * 128 + col] = pt;
        }
    }
    __syncthreads();

    sOut[(size_t)bid * HH + tid] = s2[tid] + s2[128 + tid];
    if (tid == 0) {
        float c = 0.f;
        #pragma unroll
        for (int kk = 0; kk < KK; kk++) c += mattS[kk];
        cntOut[bid] = c;
    }
}

// ---------- message kernel (layers 1,2): one node per wave, A-sides hi-only ----------

__global__ __launch_bounds__(128, 2) void msg_kernel(const float* __restrict__ mask,
                                                     const int* __restrict__ E_idx,
                                                     const unsigned short* __restrict__ hEbH,
                                                     const float* __restrict__ P,
                                                     const float* __restrict__ Q,
                                                     const short* __restrict__ W1bP,
                                                     const short* __restrict__ W2P,
                                                     const float* __restrict__ b2,
                                                     float* __restrict__ sOut,
                                                     float* __restrict__ cntOut) {
    __shared__ short AmH[2][32 * 136];

    int w = threadIdx.x >> 6, lane = threadIdx.x & 63;
    int g = blockIdx.x * 2 + w;          // node id
    int b = g >> 11;
    int m = lane & 15, q = lane >> 4;

    float maskv = mask[g];
    int erow[2][4]; float mt[2][4];
    #pragma unroll
    for (int t = 0; t < 2; t++)
        #pragma unroll
        for (int r = 0; r < 4; r++) {
            int row = t * 16 + q * 4 + r;
            erow[t][r] = E_idx[(size_t)g * KK + row];
            mt[t][r] = maskv * mask[b * NN + erow[t][r]];
        }
    {
        float c8 = mt[0][0] + mt[0][1] + mt[0][2] + mt[0][3]
                 + mt[1][0] + mt[1][1] + mt[1][2] + mt[1][3];
        c8 += __shfl_xor(c8, 16);
        c8 += __shfl_xor(c8, 32);
        if (lane == 0) cntOut[g] = c8;
    }

    float preg[8], b2reg[8];
    float qreg[8][2][4];
    #pragma unroll
    for (int nt = 0; nt < 8; nt++) {
        preg[nt]  = P[(size_t)g * HH + nt * 16 + m];
        b2reg[nt] = b2[nt * 16 + m];
        #pragma unroll
        for (int t = 0; t < 2; t++)
            #pragma unroll
            for (int r = 0; r < 4; r++)
                qreg[nt][t][r] = Q[((size_t)b * NN + erow[t][r]) * HH + nt * 16 + m];
    }

    // phase 1: m1 = relu(P + Q[nbr] + h_E @ W1b)
    {
        const unsigned short* hbH = hEbH + (size_t)g * (KK * HH);
        short8 aheH[2][4];
        #pragma unroll
        for (int t = 0; t < 2; t++)
            #pragma unroll
            for (int kc = 0; kc < 4; kc++)
                aheH[t][kc] = *(const short8*)(hbH + (t * 16 + m) * HH + kc * 32 + q * 8);
        #pragma unroll
        for (int nt = 0; nt < 8; nt++) {
            f32x4 t0 = {0.f, 0.f, 0.f, 0.f}, t1 = {0.f, 0.f, 0.f, 0.f};
            #pragma unroll
            for (int kc = 0; kc < 4; kc++) {
                const short* Bp = &W1bP[((nt * 4 + kc) * 64 + lane) * 8];
                short8 bh = *(const short8*)Bp, bl = *(const short8*)(Bp + 16384);
                t0 = MFMA16(aheH[0][kc], bh, t0);
                t0 = MFMA16(aheH[0][kc], bl, t0);
                t1 = MFMA16(aheH[1][kc], bh, t1);
                t1 = MFMA16(aheH[1][kc], bl, t1);
            }
            int col = nt * 16 + m;
            float pp = preg[nt];
            #pragma unroll
            for (int r = 0; r < 4; r++) {
                float v0 = fmaxf(t0[r] + pp + qreg[nt][0][r], 0.f);
                AmH[w][(q * 4 + r) * 136 + col] = (short)f2bf(v0);
                float v1 = fmaxf(t1[r] + pp + qreg[nt][1][r], 0.f);
                AmH[w][(16 + q * 4 + r) * 136 + col] = (short)f2bf(v1);
            }
        }
    }
    __syncthreads();

    // phase 2: m2 = relu(m1 @ W2 + b2); masked sum over 32 edges
    {
        short8 amh[2][4];
        #pragma unroll
        for (int t = 0; t < 2; t++)
            #pragma unroll
            for (int kc = 0; kc < 4; kc++)
                amh[t][kc] = *(const short8*)&AmH[w][(t * 16 + m) * 136 + kc * 32 + q * 8];
        #pragma unroll
        for (int nt = 0; nt < 8; nt++) {
            float bc = b2reg[nt];
            f32x4 a0 = {bc, bc, bc, bc}, a1 = {bc, bc, bc, bc};
            #pragma unroll
            for (int kc = 0; kc < 4; kc++) {
                const short* Bp = &W2P[((nt * 4 + kc) * 64 + lane) * 8];
                short8 bh = *(const short8*)Bp, bl = *(const short8*)(Bp + 16384);
                a0 = MFMA16(amh[0][kc], bh, a0);
                a0 = MFMA16(amh[0][kc], bl, a0);
                a1 = MFMA16(amh[1][kc], bh, a1);
                a1 = MFMA16(amh[1][kc], bl, a1);
            }
            float part = 0.f;
            #pragma unroll
            for (int r = 0; r < 4; r++)
                part += fmaxf(a0[r], 0.f) * mt[0][r] + fmaxf(a1[r], 0.f) * mt[1][r];
            part += __shfl_xor(part, 16);
            part += __shfl_xor(part, 32);
            if (q == 0) sOut[(size_t)g * HH + nt * 16 + m] = part;
        }
    }
}

// ---------- node kernel: 4 waves, A-sides hi-only ----------

#define HSTR 520   // LDS stride (shorts) for 512-wide hidden staging

__global__ __launch_bounds__(256, 3) void node_kernel(const float* __restrict__ mask,
                                                      const float* __restrict__ sbuf,
                                                      const float* __restrict__ cntb,
                                                      const float* __restrict__ hVin,
                                                      const short* __restrict__ W3P,
                                                      const float* __restrict__ b3,
                                                      const short* __restrict__ WiP,
                                                      const float* __restrict__ biN,
                                                      const short* __restrict__ WoP,
                                                      const float* __restrict__ boN,
                                                      const float* __restrict__ g0,
                                                      const float* __restrict__ h0,
                                                      const float* __restrict__ g1,
                                                      const float* __restrict__ h1,
                                                      const short* __restrict__ W1P,
                                                      const float* __restrict__ b1n,
                                                      float* __restrict__ hVout,
                                                      float* __restrict__ Pn,
                                                      float* __restrict__ Qn) {
    __shared__ short rbH[16 * 136];
    __shared__ short hbH[16 * HSTR];
    __shared__ float redS[4][2][16];
    __shared__ float g0S[128], h0S[128], g1S[128], h1S[128], b3S[128], boS[128], b1S[128];
    __shared__ float biS[512];

    int tid = threadIdx.x;
    int w = tid >> 6, lane = tid & 63;
    int m = lane & 15, q = lane >> 4;
    int rowT = blockIdx.x * 16;

    for (int i = tid; i < 128; i += 256) {
        g0S[i] = g0[i]; h0S[i] = h0[i]; g1S[i] = g1[i]; h1S[i] = h1[i];
        b3S[i] = b3[i]; boS[i] = boN[i]; b1S[i] = W1P ? b1n[i] : 0.f;
    }
    for (int i = tid; i < 512; i += 256) biS[i] = biN[i];
    __syncthreads();

    short8 ash[4];
    #pragma unroll
    for (int kc = 0; kc < 4; kc++) {
        const float* sp = &sbuf[(size_t)(rowT + m) * HH + kc * 32 + q * 8];
        f32x4 x0 = *(const f32x4*)sp;
        f32x4 x1 = *(const f32x4*)(sp + 4);
        ash[kc] = cvt8h(x0, x1);
    }
    float cntr[4];
    #pragma unroll
    for (int r = 0; r < 4; r++) cntr[r] = cntb[rowT + q * 4 + r];

    f32x4 vC2[2];
    #pragma unroll
    for (int t = 0; t < 2; t++) {
        int nt = 2 * w + t;
        f32x4 a = {0.f, 0.f, 0.f, 0.f};
        #pragma unroll
        for (int kc = 0; kc < 4; kc++) {
            const short* Bp = &W3P[((nt * 4 + kc) * 64 + lane) * 8];
            short8 bh = *(const short8*)Bp, bl = *(const short8*)(Bp + 16384);
            a = MFMA16(ash[kc], bh, a);
            a = MFMA16(ash[kc], bl, a);
        }
        int col = nt * 16 + m;
        #pragma unroll
        for (int r = 0; r < 4; r++) {
            float tv = (a[r] + cntr[r] * b3S[col]) * (1.f / 30.f);
            a[r] = hVin[(size_t)(rowT + q * 4 + r) * HH + col] + tv;
        }
        vC2[t] = a;
    }

    // LN0 (cross-wave)
    {
        float su[4] = {0, 0, 0, 0}, sq[4] = {0, 0, 0, 0};
        #pragma unroll
        for (int t = 0; t < 2; t++)
            #pragma unroll
            for (int r = 0; r < 4; r++) { float v = vC2[t][r]; su[r] += v; sq[r] += v * v; }
        #pragma unroll
        for (int off = 1; off <= 8; off <<= 1)
            #pragma unroll
            for (int r = 0; r < 4; r++) { su[r] += __shfl_xor(su[r], off); sq[r] += __shfl_xor(sq[r], off); }
        if (m == 0) {
            #pragma unroll
            for (int r = 0; r < 4; r++) { redS[w][0][q * 4 + r] = su[r]; redS[w][1][q * 4 + r] = sq[r]; }
        }
    }
    __syncthreads();
    float mu[4], inv[4];
    #pragma unroll
    for (int r = 0; r < 4; r++) {
        int row = q * 4 + r;
        float S  = redS[0][0][row] + redS[1][0][row] + redS[2][0][row] + redS[3][0][row];
        float Q2 = redS[0][1][row] + redS[1][1][row] + redS[2][1][row] + redS[3][1][row];
        mu[r] = S * (1.f / HH);
        float var = (Q2 - (float)HH * mu[r] * mu[r]) * (1.f / (HH - 1));
        inv[r] = 1.f / (sqrtf(var + EPSF) + EPSF);
    }
    #pragma unroll
    for (int t = 0; t < 2; t++) {
        int col = (2 * w + t) * 16 + m;
        #pragma unroll
        for (int r = 0; r < 4; r++)
            vC2[t][r] = g0S[col] * (vC2[t][r] - mu[r]) * inv[r] + h0S[col];
    }
    #pragma unroll
    for (int t = 0; t < 2; t++) {
        int col = (2 * w + t) * 16 + m;
        #pragma unroll
        for (int r = 0; r < 4; r++)
            rbH[(q * 4 + r) * 136 + col] = (short)f2bf(vC2[t][r]);
    }
    __syncthreads();

    short8 avh[4];
    #pragma unroll
    for (int kc = 0; kc < 4; kc++)
        avh[kc] = *(const short8*)&rbH[m * 136 + kc * 32 + q * 8];

    // FFN-in: wave's 128 hidden cols
    #pragma unroll
    for (int nt2 = 0; nt2 < 8; nt2++) {
        int jcol = w * 128 + nt2 * 16 + m;
        float bb = biS[jcol];
        f32x4 a = {bb, bb, bb, bb};
        #pragma unroll
        for (int kc = 0; kc < 4; kc++) {
            const short* Bp = &WiP[(((w * 8 + nt2) * 4 + kc) * 64 + lane) * 8];
            short8 bh = *(const short8*)Bp, bl = *(const short8*)(Bp + 65536);
            a = MFMA16(avh[kc], bh, a);
            a = MFMA16(avh[kc], bl, a);
        }
        #pragma unroll
        for (int r = 0; r < 4; r++)
            hbH[(q * 4 + r) * HSTR + jcol] = (short)f2bf(fmaxf(a[r], 0.f));
    }
    __syncthreads();

    // FFN-out: wave's 2 col-tiles over ALL 512 hidden
    f32x4 oC2[2] = {{0.f, 0.f, 0.f, 0.f}, {0.f, 0.f, 0.f, 0.f}};
    for (int kc2 = 0; kc2 < 16; kc2++) {
        short8 ahh = *(const short8*)&hbH[m * HSTR + kc2 * 32 + q * 8];
        #pragma unroll
        for (int t = 0; t < 2; t++) {
            int nt = 2 * w + t;
            const short* Bp = &WoP[((nt * 16 + kc2) * 64 + lane) * 8];
            short8 bh = *(const short8*)Bp, bl = *(const short8*)(Bp + 65536);
            oC2[t] = MFMA16(ahh, bh, oC2[t]);
            oC2[t] = MFMA16(ahh, bl, oC2[t]);
        }
    }
    #pragma unroll
    for (int t = 0; t < 2; t++) {
        int col = (2 * w + t) * 16 + m;
        #pragma unroll
        for (int r = 0; r < 4; r++)
            oC2[t][r] += boS[col] + vC2[t][r];
    }

    // LN1 (cross-wave)
    {
        float su[4] = {0, 0, 0, 0}, sq[4] = {0, 0, 0, 0};
        #pragma unroll
        for (int t = 0; t < 2; t++)
            #pragma unroll
            for (int r = 0; r < 4; r++) { float v = oC2[t][r]; su[r] += v; sq[r] += v * v; }
        #pragma unroll
        for (int off = 1; off <= 8; off <<= 1)
            #pragma unroll
            for (int r = 0; r < 4; r++) { su[r] += __shfl_xor(su[r], off); sq[r] += __shfl_xor(sq[r], off); }
        __syncthreads();   // redS reuse
        if (m == 0) {
            #pragma unroll
            for (int r = 0; r < 4; r++) { redS[w][0][q * 4 + r] = su[r]; redS[w][1][q * 4 + r] = sq[r]; }
        }
    }
    __syncthreads();
    #pragma unroll
    for (int r = 0; r < 4; r++) {
        int row = q * 4 + r;
        float S  = redS[0][0][row] + redS[1][0][row] + redS[2][0][row] + redS[3][0][row];
        float Q2 = redS[0][1][row] + redS[1][1][row] + redS[2][1][row] + redS[3][1][row];
        mu[r] = S * (1.f / HH);
        float var = (Q2 - (float)HH * mu[r] * mu[r]) * (1.f / (HH - 1));
        inv[r] = 1.f / (sqrtf(var + EPSF) + EPSF);
    }
    float mk[4];
    #pragma unroll
    for (int r = 0; r < 4; r++) mk[r] = mask[rowT + q * 4 + r];
    #pragma unroll
    for (int t = 0; t < 2; t++) {
        int col = (2 * w + t) * 16 + m;
        #pragma unroll
        for (int r = 0; r < 4; r++) {
            float y = g1S[col] * (oC2[t][r] - mu[r]) * inv[r] + h1S[col];
            y *= mk[r];
            oC2[t][r] = y;
            hVout[(size_t)(rowT + q * 4 + r) * HH + col] = y;
        }
    }

    // fused next-layer premix (wave's 4 of 16 col-tiles)
    if (W1P) {
        __syncthreads();
        #pragma unroll
        for (int t = 0; t < 2; t++) {
            int col = (2 * w + t) * 16 + m;
            #pragma unroll
            for (int r = 0; r < 4; r++)
                rbH[(q * 4 + r) * 136 + col] = (short)f2bf(oC2[t][r]);
        }
        __syncthreads();
        short8 ayh[4];
        #pragma unroll
        for (int kc = 0; kc < 4; kc++)
            ayh[kc] = *(const short8*)&rbH[m * 136 + kc * 32 + q * 8];
        #pragma unroll
        for (int u = 0; u < 4; u++) {
            int nt = w * 4 + u;
            int col = nt * 16 + m;
            float b0 = (nt < 8) ? b1S[col] : 0.f;
            f32x4 a = {b0, b0, b0, b0};
            #pragma unroll
            for (int kc = 0; kc < 4; kc++) {
                const short* Bp = &W1P[((nt * 4 + kc) * 64 + lane) * 8];
                short8 bh = *(const short8*)Bp, bl = *(const short8*)(Bp + 32768);
                a = MFMA16(ayh[kc], bh, a);
                a = MFMA16(ayh[kc], bl, a);
            }
            #pragma unroll
            for (int r = 0; r < 4; r++) {
                size_t row = rowT + q * 4 + r;
                if (nt < 8) Pn[row * HH + col] = a[r];
                else        Qn[row * HH + (col - 128)] = a[r];
            }
        }
    }
}

// ---------- launch ----------

extern "C" void kernel_launch(void* const* d_in, const int* in_sizes, int n_in,
                              void* d_out, int out_size, void* d_ws, size_t ws_size,
                              hipStream_t stream) {
    const float* X    = (const float*)d_in[0];
    const float* mask = (const float*)d_in[1];
    const float* Wn   = (const float*)d_in[2];
    const float* bn   = (const float*)d_in[3];
    const float* gn   = (const float*)d_in[4];
    const float* hn   = (const float*)d_in[5];
    const float* We   = (const float*)d_in[6];
    const float* be   = (const float*)d_in[7];
    const float* ge   = (const float*)d_in[8];
    const float* he   = (const float*)d_in[9];
    const float* Wv   = (const float*)d_in[10];
    const float* bv   = (const float*)d_in[11];
    const float* Wq   = (const float*)d_in[12];
    const float* bq   = (const float*)d_in[13];
    const float* lW1  = (const float*)d_in[14];
    const float* lb1  = (const float*)d_in[15];
    const float* lW2  = (const float*)d_in[16];
    const float* lb2  = (const float*)d_in[17];
    const float* lW3  = (const float*)d_in[18];
    const float* lb3  = (const float*)d_in[19];
    const float* lWi  = (const float*)d_in[20];
    const float* lbi  = (const float*)d_in[21];
    const float* lWo  = (const float*)d_in[22];
    const float* lbo  = (const float*)d_in[23];
    const float* lg0  = (const float*)d_in[24];
    const float* lh0  = (const float*)d_in[25];
    const float* lg1  = (const float*)d_in[26];
    const float* lh1  = (const float*)d_in[27];

    char* ws = (char*)d_ws;
    size_t off = 0;
    auto alloc = [&](size_t nbytes) { void* p = ws + off; off += (nbytes + 15) & ~(size_t)15; return p; };
    int*   E_idx = (int*)  alloc((size_t)BB * NN * KK * 4);
    float* D_nb  = (float*)alloc((size_t)BB * NN * KK * 4);
    float* ADb   = (float*)alloc((size_t)BB * NN * 3 * 4);
    float* Ofb   = (float*)alloc((size_t)BB * NN * 9 * 4);
    float* hV    = (float*)alloc((size_t)BB * NN * HH * 4);
    unsigned short* hEbH = (unsigned short*)alloc((size_t)BB * NN * KK * HH * 2);
    float* Pb    = (float*)alloc((size_t)BB * NN * HH * 4);
    float* Qb    = (float*)alloc((size_t)BB * NN * HH * 4);
    float* sBuf  = (float*)alloc((size_t)BB * NN * HH * 4);
    float* cntB  = (float*)alloc((size_t)BB * NN * 4);
    short* WeP   = (short*)alloc(2 * 8192 * 2);
    short* WqP   = (short*)alloc(2 * 16384 * 2);
    short* W1bP  = (short*)alloc(3 * 2 * 16384 * 2);
    short* W2P   = (short*)alloc(3 * 2 * 16384 * 2);
    short* W3P   = (short*)alloc(3 * 2 * 16384 * 2);
    short* WiP   = (short*)alloc(3 * 2 * 65536 * 2);
    short* WoP   = (short*)alloc(3 * 2 * 65536 * 2);
    short* W1acP = (short*)alloc(3 * 2 * 32768 * 2);
    if (off > ws_size) return;

    pack_kernel<<<2592, 256, 0, stream>>>(We, Wq, lW1, lW2, lW3, lWi, lWo,
                                          WeP, WqP, W1bP, W2P, W3P, WiP, WoP, W1acP);
    knn_kernel<<<BB * NN / 4, 256, 0, stream>>>(X, mask, E_idx, D_nb);
    orient_kernel<<<(BB * NN + 255) / 256, 256, 0, stream>>>(X, ADb, Ofb);
    node_feat_kernel<<<BB * NN, HH, 0, stream>>>(ADb, Wn, bn, gn, hn, Wv, bv,
                                                 lW1, lb1, hV, Pb, Qb);
    // edge features + fused layer-0 message pass (consumes P/Q from node_feat)
    edge_feat_kernel<<<BB * NN, HH, 0, stream>>>(X, E_idx, D_nb, Ofb,
                                                 be, ge, he, bq, WeP, WqP,
                                                 mask, Pb, Qb, W1bP, W2P, lb2,
                                                 hEbH, sBuf, cntB);

    for (int l = 0; l < 3; l++) {
        int last = (l == 2);
        if (l > 0) {
            msg_kernel<<<BB * NN / 2, HH, 0, stream>>>(
                mask, E_idx, hEbH, Pb, Qb,
                W1bP + (size_t)l * 32768,
                W2P + (size_t)l * 32768, lb2 + (size_t)l * HH,
                sBuf, cntB);
        }
        node_kernel<<<BB * NN / 16, 256, 0, stream>>>(
            mask, sBuf, cntB, hV,
            W3P + (size_t)l * 32768, lb3 + (size_t)l * HH,
            WiP + (size_t)l * 131072, lbi + (size_t)l * DFF,
            WoP + (size_t)l * 131072, lbo + (size_t)l * HH,
            lg0 + (size_t)l * HH, lh0 + (size_t)l * HH,
            lg1 + (size_t)l * HH, lh1 + (size_t)l * HH,
            last ? nullptr : (W1acP + (size_t)(l + 1) * 65536),
            last ? nullptr : (lb1 + (size_t)(l + 1) * HH),
            last ? (float*)d_out : hV,
            Pb, Qb);
    }
}

// Round 14
// 417.982 us; speedup vs baseline: 1.1275x; 1.1275x over previous
//
#include <hip/hip_runtime.h>
#include <math.h>

typedef __attribute__((ext_vector_type(8))) short short8;
typedef __attribute__((ext_vector_type(4))) float f32x4;

#define BB 2
#define NN 2048
#define KK 32
#define HH 128
#define DFF 512
#define EPSF 1e-6f
#define INFV 1e30f

#define MFMA16(a, b, c) __builtin_amdgcn_mfma_f32_16x16x32_bf16((a), (b), (c), 0, 0, 0)

// ---------- helpers ----------

__device__ __forceinline__ unsigned short f2bf(float f) {
    unsigned u = __float_as_uint(f);
    u += 0x7fffu + ((u >> 16) & 1u);          // round-to-nearest-even
    return (unsigned short)(u >> 16);
}

__device__ __forceinline__ float bf2f(unsigned short h) {
    return __uint_as_float(((unsigned)h) << 16);
}

// split x into hi+lo bf16 pair — WEIGHTS only (systematic error must stay split)
__device__ __forceinline__ void f2bf2(float x, short& hi, short& lo) {
    unsigned short h = f2bf(x);
    hi = (short)h;
    lo = (short)f2bf(x - bf2f(h));
}

// pack 8 floats -> hi-plane short8
__device__ __forceinline__ short8 cvt8h(f32x4 a, f32x4 b) {
    short8 h8;
    #pragma unroll
    for (int i = 0; i < 4; i++) h8[i] = (short)f2bf(a[i]);
    #pragma unroll
    for (int i = 0; i < 4; i++) h8[4 + i] = (short)f2bf(b[i]);
    return h8;
}

__device__ __forceinline__ float sgnf(float x) {
    return (x > 0.f) ? 1.f : ((x < 0.f) ? -1.f : 0.f);
}

__device__ __forceinline__ void norm3(float& x, float& y, float& z) {
    float n = sqrtf(x * x + y * y + z * z);
    n = fmaxf(n, 1e-12f);
    x /= n; y /= n; z /= n;
}

// block of 128 threads: sum over all threads, broadcast. 2 barriers.
__device__ __forceinline__ float blk2sum(float v, float* slots) {
    int lane = threadIdx.x & 63, wid = threadIdx.x >> 6;
    #pragma unroll
    for (int off = 32; off > 0; off >>= 1) v += __shfl_down(v, off);
    if (lane == 0) slots[wid] = v;
    __syncthreads();
    float r = slots[0] + slots[1];
    __syncthreads();
    return r;
}

// LN stats over 128 cols held in C-fragment layout (8 nt x f32x4)
__device__ __forceinline__ void lnC(const f32x4* vC, float* mu, float* inv) {
    float su[4] = {0, 0, 0, 0}, sq[4] = {0, 0, 0, 0};
    #pragma unroll
    for (int nt = 0; nt < 8; nt++)
        #pragma unroll
        for (int r = 0; r < 4; r++) { float v = vC[nt][r]; su[r] += v; sq[r] += v * v; }
    #pragma unroll
    for (int off = 1; off <= 8; off <<= 1)
        #pragma unroll
        for (int r = 0; r < 4; r++) { su[r] += __shfl_xor(su[r], off); sq[r] += __shfl_xor(sq[r], off); }
    #pragma unroll
    for (int r = 0; r < 4; r++) {
        mu[r] = su[r] * (1.f / HH);
        float var = (sq[r] - (float)HH * mu[r] * mu[r]) * (1.f / (HH - 1));
        inv[r] = 1.f / (sqrtf(var + EPSF) + EPSF);
    }
}

// ---------- kNN v5: 4 independent waves per block, ballot fast-path tiebreak ----------

__global__ __launch_bounds__(256) void knn_kernel(const float* __restrict__ X,
                                                  const float* __restrict__ mask,
                                                  int* __restrict__ E_idx,
                                                  float* __restrict__ D_nb) {
    int w = threadIdx.x >> 6, lane = threadIdx.x & 63;
    int g = blockIdx.x * 4 + w;
    int b = g >> 11, n = g & 2047;
    const float* Xb = X + (size_t)b * NN * 3;
    const float* mb = mask + (size_t)b * NN;

    float xn0 = Xb[n * 3], xn1 = Xb[n * 3 + 1], xn2 = Xb[n * 3 + 2];
    float mn = mb[n];

    float Dv[32], m2a[32];
    float lmax = -1e30f;
    #pragma unroll
    for (int s = 0; s < 32; s++) {
        int j = s * 64 + lane;
        float dx = Xb[j * 3] - xn0, dy = Xb[j * 3 + 1] - xn1, dz = Xb[j * 3 + 2] - xn2;
        float d = sqrtf(dx * dx + dy * dy + dz * dz + EPSF);
        float m2 = mn * mb[j];
        float v = m2 * d;
        Dv[s] = v; m2a[s] = m2;
        lmax = fmaxf(lmax, v);
    }
    #pragma unroll
    for (int off = 1; off <= 32; off <<= 1) lmax = fmaxf(lmax, __shfl_xor(lmax, off));
    float Dmax = lmax;
    #pragma unroll
    for (int s = 0; s < 32; s++) Dv[s] += (1.f - m2a[s]) * Dmax;

    // per-lane top-2 (strict < keeps earliest slot on exact ties)
    float l1 = INFV, l2 = INFV; int s1 = 0, s2 = 0;
    #pragma unroll
    for (int s = 0; s < 32; s++) {
        float v = Dv[s];
        bool lt1 = v < l1;
        bool lt2 = v < l2;
        float o1 = l1; int os1 = s1;
        l1 = lt1 ? v : l1;  s1 = lt1 ? s : s1;
        l2 = lt1 ? o1 : (lt2 ? v : l2);
        s2 = lt1 ? os1 : (lt2 ? s : s2);
    }

    unsigned used = 0u;
    float keepd = 0.f; int keepj = 0;

    for (int s = 0; s < KK; s++) {
        float m = l1;
        #pragma unroll
        for (int off = 1; off <= 32; off <<= 1) m = fminf(m, __shfl_xor(m, off));
        unsigned long long ball = __ballot(l1 == m);
        int jwin;
        if (__popcll(ball) == 1) {
            int src = (int)(__ffsll((long long)ball) - 1);
            jwin = __shfl(s1 * 64 + lane, src);
        } else {
            int jme = (l1 == m) ? (s1 * 64 + lane) : 0x7FFFFFFF;
            jwin = jme;
            #pragma unroll
            for (int off = 1; off <= 32; off <<= 1) jwin = min(jwin, __shfl_xor(jwin, off));
        }
        if (lane == s) { keepd = m; keepj = jwin; }
        if (lane == (jwin & 63)) {
            used |= 1u << s1;
            l1 = l2; s1 = s2;
            l2 = INFV;
            if (l1 >= INFV) {   // rare refill
                l1 = INFV; l2 = INFV;
                #pragma unroll
                for (int i = 0; i < 32; i++) {
                    float v = ((used >> i) & 1u) ? INFV : Dv[i];
                    bool lt1 = v < l1;
                    bool lt2 = v < l2;
                    float o1 = l1; int os1 = s1;
                    l1 = lt1 ? v : l1;  s1 = lt1 ? i : s1;
                    l2 = lt1 ? o1 : (lt2 ? v : l2);
                    s2 = lt1 ? os1 : (lt2 ? i : s2);
                }
            }
        }
    }
    if (lane < KK) {
        E_idx[(size_t)g * KK + lane] = keepj;
        D_nb[(size_t)g * KK + lane] = keepd;
    }
}

// ---------- weight pre-pack: fp32 -> (hi,lo) bf16 B-fragment planes ----------

__device__ __forceinline__ void packB(const float* __restrict__ src, short* __restrict__ dH,
                                      short* __restrict__ dL, int e, int KC, int N, int Kreal) {
    int j = e & 7, ln = (e >> 3) & 63, t = e >> 9;
    int kc = t % KC, nt = t / KC;
    int k = kc * 32 + (ln >> 4) * 8 + j;
    int n = nt * 16 + (ln & 15);
    float v = (k < Kreal) ? src[(size_t)k * N + n] : 0.f;
    short hi, lo; f2bf2(v, hi, lo);
    dH[e] = hi; dL[e] = lo;
}

__global__ __launch_bounds__(256) void pack_kernel(const float* __restrict__ We,
                                                   const float* __restrict__ Wq,
                                                   const float* __restrict__ lW1,
                                                   const float* __restrict__ lW2,
                                                   const float* __restrict__ lW3,
                                                   const float* __restrict__ lWi,
                                                   const float* __restrict__ lWo,
                                                   short* __restrict__ WeP,
                                                   short* __restrict__ WqP,
                                                   short* __restrict__ W1bP,
                                                   short* __restrict__ W2P,
                                                   short* __restrict__ W3P,
                                                   short* __restrict__ WiP,
                                                   short* __restrict__ WoP,
                                                   short* __restrict__ W1acP) {
    int e = blockIdx.x * 256 + threadIdx.x;
    if (e < 8192) { packB(We, WeP, WeP + 8192, e, 2, 128, 39); return; }
    e -= 8192;
    if (e < 16384) { packB(Wq, WqP, WqP + 16384, e, 4, 128, 128); return; }
    e -= 16384;
    if (e < 49152) {
        int l = e >> 14, r = e & 16383;
        packB(lW1 + (size_t)l * 49152 + 16384, W1bP + l * 32768, W1bP + l * 32768 + 16384, r, 4, 128, 128);
        return;
    }
    e -= 49152;
    if (e < 49152) {
        int l = e >> 14, r = e & 16383;
        packB(lW2 + (size_t)l * 16384, W2P + l * 32768, W2P + l * 32768 + 16384, r, 4, 128, 128);
        return;
    }
    e -= 49152;
    if (e < 49152) {
        int l = e >> 14, r = e & 16383;
        packB(lW3 + (size_t)l * 16384, W3P + l * 32768, W3P + l * 32768 + 16384, r, 4, 128, 128);
        return;
    }
    e -= 49152;
    if (e < 196608) {
        int l = e / 65536, r = e % 65536;
        packB(lWi + (size_t)l * 65536, WiP + l * 131072, WiP + l * 131072 + 65536, r, 4, 512, 128);
        return;
    }
    e -= 196608;
    if (e < 196608) {
        int l = e / 65536, r = e % 65536;
        packB(lWo + (size_t)l * 65536, WoP + l * 131072, WoP + l * 131072 + 65536, r, 16, 128, 512);
        return;
    }
    e -= 196608;
    if (e < 98304) {
        int l = e / 32768, r = e % 32768;
        int j = r & 7, ln = (r >> 3) & 63, t = r >> 9;
        int kc = t & 3, nt = t >> 2;
        int k = kc * 32 + (ln >> 4) * 8 + j;
        int n = nt * 16 + (ln & 15);
        const float* base = lW1 + (size_t)l * 49152;
        float v = (n < 128) ? base[(size_t)k * 128 + n] : base[(size_t)(256 + k) * 128 + (n - 128)];
        short hi, lo; f2bf2(v, hi, lo);
        short* dH = W1acP + l * 65536;
        dH[r] = hi; dH[32768 + r] = lo;
    }
}

// ---------- backbone frames ----------

__global__ void orient_kernel(const float* __restrict__ X,
                              float* __restrict__ AD,
                              float* __restrict__ Of) {
    int t = blockIdx.x * blockDim.x + threadIdx.x;
    if (t >= BB * NN) return;
    int b = t / NN, n = t % NN;
    float* ad = AD + (size_t)t * 3;
    float* of = Of + (size_t)t * 9;
    if (n < 1 || n > NN - 3) {
        ad[0] = ad[1] = ad[2] = 0.f;
        #pragma unroll
        for (int i = 0; i < 9; i++) of[i] = 0.f;
        return;
    }
    const float* Xb = X + (size_t)b * NN * 3;
    float p0x = Xb[(n - 1) * 3], p0y = Xb[(n - 1) * 3 + 1], p0z = Xb[(n - 1) * 3 + 2];
    float p1x = Xb[n * 3],       p1y = Xb[n * 3 + 1],       p1z = Xb[n * 3 + 2];
    float p2x = Xb[(n + 1) * 3], p2y = Xb[(n + 1) * 3 + 1], p2z = Xb[(n + 1) * 3 + 2];
    float p3x = Xb[(n + 2) * 3], p3y = Xb[(n + 2) * 3 + 1], p3z = Xb[(n + 2) * 3 + 2];

    float u2x = p1x - p0x, u2y = p1y - p0y, u2z = p1z - p0z; norm3(u2x, u2y, u2z);
    float u1x = p2x - p1x, u1y = p2y - p1y, u1z = p2z - p1z; norm3(u1x, u1y, u1z);
    float u0x = p3x - p2x, u0y = p3y - p2y, u0z = p3z - p2z; norm3(u0x, u0y, u0z);

    float n2x = u2y * u1z - u2z * u1y, n2y = u2z * u1x - u2x * u1z, n2z = u2x * u1y - u2y * u1x;
    norm3(n2x, n2y, n2z);
    float n1x = u1y * u0z - u1z * u0y, n1y = u1z * u0x - u1x * u0z, n1z = u1x * u0y - u1y * u0x;
    norm3(n1x, n1y, n1z);

    float cosA = -(u1x * u0x + u1y * u0y + u1z * u0z);
    cosA = fminf(fmaxf(cosA, -1.f + EPSF), 1.f - EPSF);
    float A = acosf(cosA);
    float cosD = n2x * n1x + n2y * n1y + n2z * n1z;
    cosD = fminf(fmaxf(cosD, -1.f + EPSF), 1.f - EPSF);
    float sg = sgnf(u2x * n1x + u2y * n1y + u2z * n1z);
    float Dih = sg * acosf(cosD);

    ad[0] = cosf(A);
    ad[1] = sinf(A) * cosf(Dih);
    ad[2] = sinf(A) * sinf(Dih);

    float o1x = u2x - u1x, o1y = u2y - u1y, o1z = u2z - u1z; norm3(o1x, o1y, o1z);
    float cx = o1y * n2z - o1z * n2y, cy = o1z * n2x - o1x * n2z, cz = o1x * n2y - o1y * n2x;
    of[0] = o1x; of[1] = o1y; of[2] = o1z;
    of[3] = n2x; of[4] = n2y; of[5] = n2z;
    of[6] = cx;  of[7] = cy;  of[8] = cz;
}

// ---------- node features + premix for layer 0 (fp32) ----------

__global__ __launch_bounds__(128) void node_feat_kernel(const float* __restrict__ AD,
                                                        const float* __restrict__ Wn,
                                                        const float* __restrict__ bn,
                                                        const float* __restrict__ gn,
                                                        const float* __restrict__ hn,
                                                        const float* __restrict__ Wv,
                                                        const float* __restrict__ bv,
                                                        const float* __restrict__ W1_0,
                                                        const float* __restrict__ b1_0,
                                                        float* __restrict__ hV,
                                                        float* __restrict__ P,
                                                        float* __restrict__ Q) {
    __shared__ __align__(16) float y[HH];
    __shared__ float slots[2];
    int n = blockIdx.x; int h = threadIdx.x;
    float a0 = AD[n * 3], a1 = AD[n * 3 + 1], a2 = AD[n * 3 + 2];
    float v = bn[h] + a0 * Wn[h] + a1 * Wn[HH + h] + a2 * Wn[2 * HH + h];
    float mu = blk2sum(v, slots) * (1.f / HH);
    float d = v - mu;
    float var = blk2sum(d * d, slots) * (1.f / (HH - 1));
    float yv = gn[h] * d / (sqrtf(var + EPSF) + EPSF) + hn[h];
    y[h] = yv; __syncthreads();
    float acc = bv[h];
    for (int c4 = 0; c4 < 32; c4++) {
        f32x4 v4 = ((const f32x4*)y)[c4]; int c = 4 * c4;
        acc += v4.x * Wv[c * HH + h] + v4.y * Wv[(c + 1) * HH + h]
             + v4.z * Wv[(c + 2) * HH + h] + v4.w * Wv[(c + 3) * HH + h];
    }
    hV[(size_t)n * HH + h] = acc;
    __syncthreads(); y[h] = acc; __syncthreads();
    float p = b1_0[h], qv = 0.f;
    for (int c4 = 0; c4 < 32; c4++) {
        f32x4 v4 = ((const f32x4*)y)[c4]; int c = 4 * c4;
        p  += v4.x * W1_0[c * HH + h]        + v4.y * W1_0[(c + 1) * HH + h]
            + v4.z * W1_0[(c + 2) * HH + h]  + v4.w * W1_0[(c + 3) * HH + h];
        qv += v4.x * W1_0[(256 + c) * HH + h]       + v4.y * W1_0[(256 + c + 1) * HH + h]
            + v4.z * W1_0[(256 + c + 2) * HH + h]   + v4.w * W1_0[(256 + c + 3) * HH + h];
    }
    P[(size_t)n * HH + h] = p;
    Q[(size_t)n * HH + h] = qv;
}

// ---------- edge features: A-side hi-only, B-side split ----------

__global__ __launch_bounds__(128) void edge_feat_kernel(const float* __restrict__ X,
                                                        const int* __restrict__ E_idx,
                                                        const float* __restrict__ D_nb,
                                                        const float* __restrict__ Of,
                                                        const float* __restrict__ be,
                                                        const float* __restrict__ ge,
                                                        const float* __restrict__ he,
                                                        const float* __restrict__ bq,
                                                        const short* __restrict__ WeP,
                                                        const short* __restrict__ WqP,
                                                        unsigned short* __restrict__ hEbH) {
    __shared__ short AefH[32 * 72];
    __shared__ short AeH[32 * 136];
    __shared__ float beS[HH], geS[HH], heS[HH], bqS[HH];

    int bid = blockIdx.x; int b = bid >> 11, n = bid & 2047; int tid = threadIdx.x;
    int lane = tid & 63, w = tid >> 6;
    beS[tid] = be[tid]; geS[tid] = ge[tid]; heS[tid] = he[tid]; bqS[tid] = bq[tid];
    {
        unsigned* Az = (unsigned*)AefH;
        for (int i = tid; i < 32 * 72 / 2; i += 128) Az[i] = 0u;
    }
    __syncthreads();

    int part = tid >> 5, k = tid & 31;
    int e = E_idx[(size_t)bid * KK + k];
    float dpos = (float)e - (float)n;
    if (part == 1 || part == 2) {
        int p0 = (part - 1) * 4;
        #pragma unroll
        for (int p = 0; p < 4; p++) {
            float fr = expf((float)(2 * (p0 + p)) * -0.5756462732485115f);
            float ang = dpos * fr;
            AefH[k * 72 + p0 + p]     = (short)f2bf(cosf(ang));
            AefH[k * 72 + 8 + p0 + p] = (short)f2bf(sinf(ang));
        }
    } else if (part == 3) {
        float Dv = D_nb[(size_t)bid * KK + k];
        #pragma unroll
        for (int i = 0; i < 16; i++) {
            float m = (20.f / 15.f) * (float)i;
            float z = (Dv - m) * 0.8f;
            AefH[k * 72 + 16 + i] = (short)f2bf(expf(-z * z));
        }
    } else {
        const float* Omp = Of + (size_t)(b * NN + n) * 9;
        const float* Onp = Of + (size_t)(b * NN + e) * 9;
        float Om[9], On[9];
        #pragma unroll
        for (int i = 0; i < 9; i++) { Om[i] = Omp[i]; On[i] = Onp[i]; }
        float vx = X[(size_t)(b * NN + e) * 3 + 0] - X[(size_t)(b * NN + n) * 3 + 0];
        float vy = X[(size_t)(b * NN + e) * 3 + 1] - X[(size_t)(b * NN + n) * 3 + 1];
        float vz = X[(size_t)(b * NN + e) * 3 + 2] - X[(size_t)(b * NN + n) * 3 + 2];
        float t0 = Om[0] * vx + Om[1] * vy + Om[2] * vz;
        float t1 = Om[3] * vx + Om[4] * vy + Om[5] * vz;
        float t2 = Om[6] * vx + Om[7] * vy + Om[8] * vz;
        float nr = fmaxf(sqrtf(t0 * t0 + t1 * t1 + t2 * t2), 1e-12f);
        AefH[k * 72 + 32] = (short)f2bf(t0 / nr);
        AefH[k * 72 + 33] = (short)f2bf(t1 / nr);
        AefH[k * 72 + 34] = (short)f2bf(t2 / nr);
        float R[9];
        #pragma unroll
        for (int i = 0; i < 3; i++)
            #pragma unroll
            for (int l = 0; l < 3; l++)
                R[i * 3 + l] = Om[0 + i] * On[0 + l] + Om[3 + i] * On[3 + l] + Om[6 + i] * On[6 + l];
        float Rxx = R[0], Ryy = R[4], Rzz = R[8];
        float mx = 0.5f * sqrtf(fabsf(1.f + Rxx - Ryy - Rzz));
        float my = 0.5f * sqrtf(fabsf(1.f - Rxx + Ryy - Rzz));
        float mz = 0.5f * sqrtf(fabsf(1.f - Rxx - Ryy + Rzz));
        float qx = sgnf(R[7] - R[5]) * mx;
        float qy = sgnf(R[2] - R[6]) * my;
        float qz = sgnf(R[3] - R[1]) * mz;
        float qw = 0.5f * sqrtf(fmaxf(1.f + Rxx + Ryy + Rzz, 0.f));
        float qn = fmaxf(sqrtf(qx * qx + qy * qy + qz * qz + qw * qw), 1e-12f);
        AefH[k * 72 + 35] = (short)f2bf(qx / qn);
        AefH[k * 72 + 36] = (short)f2bf(qy / qn);
        AefH[k * 72 + 37] = (short)f2bf(qz / qn);
        AefH[k * 72 + 38] = (short)f2bf(qw / qn);
    }
    __syncthreads();

    int m = lane & 15, q = lane >> 4;
    int row = (w * 16 + m) * 72;
    short8 a0h = *(const short8*)&AefH[row + q * 8];
    short8 a1h = *(const short8*)&AefH[row + 32 + q * 8];
    f32x4 accA[8];
    #pragma unroll
    for (int nt = 0; nt < 8; nt++) {
        float bc = beS[nt * 16 + m];
        f32x4 acc = {bc, bc, bc, bc};
        const short* B0 = &WeP[((nt * 2 + 0) * 64 + lane) * 8];
        const short* B1 = &WeP[((nt * 2 + 1) * 64 + lane) * 8];
        short8 b0h = *(const short8*)B0, b0l = *(const short8*)(B0 + 8192);
        short8 b1h = *(const short8*)B1, b1l = *(const short8*)(B1 + 8192);
        acc = MFMA16(a0h, b0h, acc);
        acc = MFMA16(a0h, b0l, acc);
        acc = MFMA16(a1h, b1h, acc);
        acc = MFMA16(a1h, b1l, acc);
        accA[nt] = acc;
    }
    float mu[4], inv[4];
    lnC(accA, mu, inv);
    #pragma unroll
    for (int nt = 0; nt < 8; nt++) {
        int col = nt * 16 + m;
        float g = geS[col], hh = heS[col];
        #pragma unroll
        for (int r = 0; r < 4; r++) {
            int edge = w * 16 + q * 4 + r;
            float y = g * (accA[nt][r] - mu[r]) * inv[r] + hh;
            AeH[edge * 136 + col] = (short)f2bf(y);
        }
    }
    __syncthreads();

    short8 ah[4];
    #pragma unroll
    for (int kc = 0; kc < 4; kc++)
        ah[kc] = *(const short8*)&AeH[(w * 16 + m) * 136 + kc * 32 + q * 8];
    #pragma unroll
    for (int nt = 0; nt < 8; nt++) {
        int col = nt * 16 + m;
        float bc = bqS[col];
        f32x4 acc = {bc, bc, bc, bc};
        #pragma unroll
        for (int kc = 0; kc < 4; kc++) {
            const short* Bp = &WqP[((nt * 4 + kc) * 64 + lane) * 8];
            short8 bh = *(const short8*)Bp, bl = *(const short8*)(Bp + 16384);
            acc = MFMA16(ah[kc], bh, acc);
            acc = MFMA16(ah[kc], bl, acc);
        }
        #pragma unroll
        for (int r = 0; r < 4; r++) {
            int edge = w * 16 + q * 4 + r;
            hEbH[(size_t)bid * (KK * HH) + edge * HH + col] = f2bf(acc[r]);
        }
    }
}

// ---------- message kernel v6: one node per wave, all A-sides hi-only ----------

__global__ __launch_bounds__(128, 2) void msg_kernel(const float* __restrict__ mask,
                                                     const int* __restrict__ E_idx,
                                                     const unsigned short* __restrict__ hEbH,
                                                     const float* __restrict__ P,
                                                     const float* __restrict__ Q,
                                                     const short* __restrict__ W1bP,
                                                     const short* __restrict__ W2P,
                                                     const float* __restrict__ b2,
                                                     float* __restrict__ sOut,
                                                     float* __restrict__ cntOut) {
    __shared__ short AmH[2][32 * 136];

    int w = threadIdx.x >> 6, lane = threadIdx.x & 63;
    int g = blockIdx.x * 2 + w;          // node id
    int b = g >> 11;
    int m = lane & 15, q = lane >> 4;

    float maskv = mask[g];
    int erow[2][4]; float mt[2][4];
    #pragma unroll
    for (int t = 0; t < 2; t++)
        #pragma unroll
        for (int r = 0; r < 4; r++) {
            int row = t * 16 + q * 4 + r;
            erow[t][r] = E_idx[(size_t)g * KK + row];
            mt[t][r] = maskv * mask[b * NN + erow[t][r]];
        }
    {
        float c8 = mt[0][0] + mt[0][1] + mt[0][2] + mt[0][3]
                 + mt[1][0] + mt[1][1] + mt[1][2] + mt[1][3];
        c8 += __shfl_xor(c8, 16);
        c8 += __shfl_xor(c8, 32);
        if (lane == 0) cntOut[g] = c8;
    }

    float preg[8], b2reg[8];
    float qreg[8][2][4];
    #pragma unroll
    for (int nt = 0; nt < 8; nt++) {
        preg[nt]  = P[(size_t)g * HH + nt * 16 + m];
        b2reg[nt] = b2[nt * 16 + m];
        #pragma unroll
        for (int t = 0; t < 2; t++)
            #pragma unroll
            for (int r = 0; r < 4; r++)
                qreg[nt][t][r] = Q[((size_t)b * NN + erow[t][r]) * HH + nt * 16 + m];
    }

    // phase 1: m1 = relu(P + Q[nbr] + h_E @ W1b)
    {
        const unsigned short* hbH = hEbH + (size_t)g * (KK * HH);
        short8 aheH[2][4];
        #pragma unroll
        for (int t = 0; t < 2; t++)
            #pragma unroll
            for (int kc = 0; kc < 4; kc++)
                aheH[t][kc] = *(const short8*)(hbH + (t * 16 + m) * HH + kc * 32 + q * 8);
        #pragma unroll
        for (int nt = 0; nt < 8; nt++) {
            f32x4 t0 = {0.f, 0.f, 0.f, 0.f}, t1 = {0.f, 0.f, 0.f, 0.f};
            #pragma unroll
            for (int kc = 0; kc < 4; kc++) {
                const short* Bp = &W1bP[((nt * 4 + kc) * 64 + lane) * 8];
                short8 bh = *(const short8*)Bp, bl = *(const short8*)(Bp + 16384);
                t0 = MFMA16(aheH[0][kc], bh, t0);
                t0 = MFMA16(aheH[0][kc], bl, t0);
                t1 = MFMA16(aheH[1][kc], bh, t1);
                t1 = MFMA16(aheH[1][kc], bl, t1);
            }
            int col = nt * 16 + m;
            float pp = preg[nt];
            #pragma unroll
            for (int r = 0; r < 4; r++) {
                float v0 = fmaxf(t0[r] + pp + qreg[nt][0][r], 0.f);
                AmH[w][(q * 4 + r) * 136 + col] = (short)f2bf(v0);
                float v1 = fmaxf(t1[r] + pp + qreg[nt][1][r], 0.f);
                AmH[w][(16 + q * 4 + r) * 136 + col] = (short)f2bf(v1);
            }
        }
    }
    __syncthreads();

    // phase 2: m2 = relu(m1 @ W2 + b2); masked sum over 32 edges
    {
        short8 amh[2][4];
        #pragma unroll
        for (int t = 0; t < 2; t++)
            #pragma unroll
            for (int kc = 0; kc < 4; kc++)
                amh[t][kc] = *(const short8*)&AmH[w][(t * 16 + m) * 136 + kc * 32 + q * 8];
        #pragma unroll
        for (int nt = 0; nt < 8; nt++) {
            float bc = b2reg[nt];
            f32x4 a0 = {bc, bc, bc, bc}, a1 = {bc, bc, bc, bc};
            #pragma unroll
            for (int kc = 0; kc < 4; kc++) {
                const short* Bp = &W2P[((nt * 4 + kc) * 64 + lane) * 8];
                short8 bh = *(const short8*)Bp, bl = *(const short8*)(Bp + 16384);
                a0 = MFMA16(amh[0][kc], bh, a0);
                a0 = MFMA16(amh[0][kc], bl, a0);
                a1 = MFMA16(amh[1][kc], bh, a1);
                a1 = MFMA16(amh[1][kc], bl, a1);
            }
            float part = 0.f;
            #pragma unroll
            for (int r = 0; r < 4; r++)
                part += fmaxf(a0[r], 0.f) * mt[0][r] + fmaxf(a1[r], 0.f) * mt[1][r];
            part += __shfl_xor(part, 16);
            part += __shfl_xor(part, 32);
            if (q == 0) sOut[(size_t)g * HH + nt * 16 + m] = part;
        }
    }
}

// ---------- node kernel: 4 waves, A-sides hi-only ----------

#define HSTR 520   // LDS stride (shorts) for 512-wide hidden staging

__global__ __launch_bounds__(256, 3) void node_kernel(const float* __restrict__ mask,
                                                      const float* __restrict__ sbuf,
                                                      const float* __restrict__ cntb,
                                                      const float* __restrict__ hVin,
                                                      const short* __restrict__ W3P,
                                                      const float* __restrict__ b3,
                                                      const short* __restrict__ WiP,
                                                      const float* __restrict__ biN,
                                                      const short* __restrict__ WoP,
                                                      const float* __restrict__ boN,
                                                      const float* __restrict__ g0,
                                                      const float* __restrict__ h0,
                                                      const float* __restrict__ g1,
                                                      const float* __restrict__ h1,
                                                      const short* __restrict__ W1P,
                                                      const float* __restrict__ b1n,
                                                      float* __restrict__ hVout,
                                                      float* __restrict__ Pn,
                                                      float* __restrict__ Qn) {
    __shared__ short rbH[16 * 136];
    __shared__ short hbH[16 * HSTR];
    __shared__ float redS[4][2][16];
    __shared__ float g0S[128], h0S[128], g1S[128], h1S[128], b3S[128], boS[128], b1S[128];
    __shared__ float biS[512];

    int tid = threadIdx.x;
    int w = tid >> 6, lane = tid & 63;
    int m = lane & 15, q = lane >> 4;
    int rowT = blockIdx.x * 16;

    for (int i = tid; i < 128; i += 256) {
        g0S[i] = g0[i]; h0S[i] = h0[i]; g1S[i] = g1[i]; h1S[i] = h1[i];
        b3S[i] = b3[i]; boS[i] = boN[i]; b1S[i] = W1P ? b1n[i] : 0.f;
    }
    for (int i = tid; i < 512; i += 256) biS[i] = biN[i];
    __syncthreads();

    short8 ash[4];
    #pragma unroll
    for (int kc = 0; kc < 4; kc++) {
        const float* sp = &sbuf[(size_t)(rowT + m) * HH + kc * 32 + q * 8];
        f32x4 x0 = *(const f32x4*)sp;
        f32x4 x1 = *(const f32x4*)(sp + 4);
        ash[kc] = cvt8h(x0, x1);
    }
    float cntr[4];
    #pragma unroll
    for (int r = 0; r < 4; r++) cntr[r] = cntb[rowT + q * 4 + r];

    f32x4 vC2[2];
    #pragma unroll
    for (int t = 0; t < 2; t++) {
        int nt = 2 * w + t;
        f32x4 a = {0.f, 0.f, 0.f, 0.f};
        #pragma unroll
        for (int kc = 0; kc < 4; kc++) {
            const short* Bp = &W3P[((nt * 4 + kc) * 64 + lane) * 8];
            short8 bh = *(const short8*)Bp, bl = *(const short8*)(Bp + 16384);
            a = MFMA16(ash[kc], bh, a);
            a = MFMA16(ash[kc], bl, a);
        }
        int col = nt * 16 + m;
        #pragma unroll
        for (int r = 0; r < 4; r++) {
            float tv = (a[r] + cntr[r] * b3S[col]) * (1.f / 30.f);
            a[r] = hVin[(size_t)(rowT + q * 4 + r) * HH + col] + tv;
        }
        vC2[t] = a;
    }

    // LN0 (cross-wave)
    {
        float su[4] = {0, 0, 0, 0}, sq[4] = {0, 0, 0, 0};
        #pragma unroll
        for (int t = 0; t < 2; t++)
            #pragma unroll
            for (int r = 0; r < 4; r++) { float v = vC2[t][r]; su[r] += v; sq[r] += v * v; }
        #pragma unroll
        for (int off = 1; off <= 8; off <<= 1)
            #pragma unroll
            for (int r = 0; r < 4; r++) { su[r] += __shfl_xor(su[r], off); sq[r] += __shfl_xor(sq[r], off); }
        if (m == 0) {
            #pragma unroll
            for (int r = 0; r < 4; r++) { redS[w][0][q * 4 + r] = su[r]; redS[w][1][q * 4 + r] = sq[r]; }
        }
    }
    __syncthreads();
    float mu[4], inv[4];
    #pragma unroll
    for (int r = 0; r < 4; r++) {
        int row = q * 4 + r;
        float S  = redS[0][0][row] + redS[1][0][row] + redS[2][0][row] + redS[3][0][row];
        float Q2 = redS[0][1][row] + redS[1][1][row] + redS[2][1][row] + redS[3][1][row];
        mu[r] = S * (1.f / HH);
        float var = (Q2 - (float)HH * mu[r] * mu[r]) * (1.f / (HH - 1));
        inv[r] = 1.f / (sqrtf(var + EPSF) + EPSF);
    }
    #pragma unroll
    for (int t = 0; t < 2; t++) {
        int col = (2 * w + t) * 16 + m;
        #pragma unroll
        for (int r = 0; r < 4; r++)
            vC2[t][r] = g0S[col] * (vC2[t][r] - mu[r]) * inv[r] + h0S[col];
    }
    #pragma unroll
    for (int t = 0; t < 2; t++) {
        int col = (2 * w + t) * 16 + m;
        #pragma unroll
        for (int r = 0; r < 4; r++)
            rbH[(q * 4 + r) * 136 + col] = (short)f2bf(vC2[t][r]);
    }
    __syncthreads();

    short8 avh[4];
    #pragma unroll
    for (int kc = 0; kc < 4; kc++)
        avh[kc] = *(const short8*)&rbH[m * 136 + kc * 32 + q * 8];

    // FFN-in: wave's 128 hidden cols
    #pragma unroll
    for (int nt2 = 0; nt2 < 8; nt2++) {
        int jcol = w * 128 + nt2 * 16 + m;
        float bb = biS[jcol];
        f32x4 a = {bb, bb, bb, bb};
        #pragma unroll
        for (int kc = 0; kc < 4; kc++) {
            const short* Bp = &WiP[(((w * 8 + nt2) * 4 + kc) * 64 + lane) * 8];
            short8 bh = *(const short8*)Bp, bl = *(const short8*)(Bp + 65536);
            a = MFMA16(avh[kc], bh, a);
            a = MFMA16(avh[kc], bl, a);
        }
        #pragma unroll
        for (int r = 0; r < 4; r++)
            hbH[(q * 4 + r) * HSTR + jcol] = (short)f2bf(fmaxf(a[r], 0.f));
    }
    __syncthreads();

    // FFN-out: wave's 2 col-tiles over ALL 512 hidden
    f32x4 oC2[2] = {{0.f, 0.f, 0.f, 0.f}, {0.f, 0.f, 0.f, 0.f}};
    for (int kc2 = 0; kc2 < 16; kc2++) {
        short8 ahh = *(const short8*)&hbH[m * HSTR + kc2 * 32 + q * 8];
        #pragma unroll
        for (int t = 0; t < 2; t++) {
            int nt = 2 * w + t;
            const short* Bp = &WoP[((nt * 16 + kc2) * 64 + lane) * 8];
            short8 bh = *(const short8*)Bp, bl = *(const short8*)(Bp + 65536);
            oC2[t] = MFMA16(ahh, bh, oC2[t]);
            oC2[t] = MFMA16(ahh, bl, oC2[t]);
        }
    }
    #pragma unroll
    for (int t = 0; t < 2; t++) {
        int col = (2 * w + t) * 16 + m;
        #pragma unroll
        for (int r = 0; r < 4; r++)
            oC2[t][r] += boS[col] + vC2[t][r];
    }

    // LN1 (cross-wave)
    {
        float su[4] = {0, 0, 0, 0}, sq[4] = {0, 0, 0, 0};
        #pragma unroll
        for (int t = 0; t < 2; t++)
            #pragma unroll
            for (int r = 0; r < 4; r++) { float v = oC2[t][r]; su[r] += v; sq[r] += v * v; }
        #pragma unroll
        for (int off = 1; off <= 8; off <<= 1)
            #pragma unroll
            for (int r = 0; r < 4; r++) { su[r] += __shfl_xor(su[r], off); sq[r] += __shfl_xor(sq[r], off); }
        __syncthreads();   // redS reuse
        if (m == 0) {
            #pragma unroll
            for (int r = 0; r < 4; r++) { redS[w][0][q * 4 + r] = su[r]; redS[w][1][q * 4 + r] = sq[r]; }
        }
    }
    __syncthreads();
    #pragma unroll
    for (int r = 0; r < 4; r++) {
        int row = q * 4 + r;
        float S  = redS[0][0][row] + redS[1][0][row] + redS[2][0][row] + redS[3][0][row];
        float Q2 = redS[0][1][row] + redS[1][1][row] + redS[2][1][row] + redS[3][1][row];
        mu[r] = S * (1.f / HH);
        float var = (Q2 - (float)HH * mu[r] * mu[r]) * (1.f / (HH - 1));
        inv[r] = 1.f / (sqrtf(var + EPSF) + EPSF);
    }
    float mk[4];
    #pragma unroll
    for (int r = 0; r < 4; r++) mk[r] = mask[rowT + q * 4 + r];
    #pragma unroll
    for (int t = 0; t < 2; t++) {
        int col = (2 * w + t) * 16 + m;
        #pragma unroll
        for (int r = 0; r < 4; r++) {
            float y = g1S[col] * (oC2[t][r] - mu[r]) * inv[r] + h1S[col];
            y *= mk[r];
            oC2[t][r] = y;
            hVout[(size_t)(rowT + q * 4 + r) * HH + col] = y;
        }
    }

    // fused next-layer premix (wave's 4 of 16 col-tiles)
    if (W1P) {
        __syncthreads();
        #pragma unroll
        for (int t = 0; t < 2; t++) {
            int col = (2 * w + t) * 16 + m;
            #pragma unroll
            for (int r = 0; r < 4; r++)
                rbH[(q * 4 + r) * 136 + col] = (short)f2bf(oC2[t][r]);
        }
        __syncthreads();
        short8 ayh[4];
        #pragma unroll
        for (int kc = 0; kc < 4; kc++)
            ayh[kc] = *(const short8*)&rbH[m * 136 + kc * 32 + q * 8];
        #pragma unroll
        for (int u = 0; u < 4; u++) {
            int nt = w * 4 + u;
            int col = nt * 16 + m;
            float b0 = (nt < 8) ? b1S[col] : 0.f;
            f32x4 a = {b0, b0, b0, b0};
            #pragma unroll
            for (int kc = 0; kc < 4; kc++) {
                const short* Bp = &W1P[((nt * 4 + kc) * 64 + lane) * 8];
                short8 bh = *(const short8*)Bp, bl = *(const short8*)(Bp + 32768);
                a = MFMA16(ayh[kc], bh, a);
                a = MFMA16(ayh[kc], bl, a);
            }
            #pragma unroll
            for (int r = 0; r < 4; r++) {
                size_t row = rowT + q * 4 + r;
                if (nt < 8) Pn[row * HH + col] = a[r];
                else        Qn[row * HH + (col - 128)] = a[r];
            }
        }
    }
}

// ---------- launch ----------

extern "C" void kernel_launch(void* const* d_in, const int* in_sizes, int n_in,
                              void* d_out, int out_size, void* d_ws, size_t ws_size,
                              hipStream_t stream) {
    const float* X    = (const float*)d_in[0];
    const float* mask = (const float*)d_in[1];
    const float* Wn   = (const float*)d_in[2];
    const float* bn   = (const float*)d_in[3];
    const float* gn   = (const float*)d_in[4];
    const float* hn   = (const float*)d_in[5];
    const float* We   = (const float*)d_in[6];
    const float* be   = (const float*)d_in[7];
    const float* ge   = (const float*)d_in[8];
    const float* he   = (const float*)d_in[9];
    const float* Wv   = (const float*)d_in[10];
    const float* bv   = (const float*)d_in[11];
    const float* Wq   = (const float*)d_in[12];
    const float* bq   = (const float*)d_in[13];
    const float* lW1  = (const float*)d_in[14];
    const float* lb1  = (const float*)d_in[15];
    const float* lW2  = (const float*)d_in[16];
    const float* lb2  = (const float*)d_in[17];
    const float* lW3  = (const float*)d_in[18];
    const float* lb3  = (const float*)d_in[19];
    const float* lWi  = (const float*)d_in[20];
    const float* lbi  = (const float*)d_in[21];
    const float* lWo  = (const float*)d_in[22];
    const float* lbo  = (const float*)d_in[23];
    const float* lg0  = (const float*)d_in[24];
    const float* lh0  = (const float*)d_in[25];
    const float* lg1  = (const float*)d_in[26];
    const float* lh1  = (const float*)d_in[27];

    char* ws = (char*)d_ws;
    size_t off = 0;
    auto alloc = [&](size_t nbytes) { void* p = ws + off; off += (nbytes + 15) & ~(size_t)15; return p; };
    int*   E_idx = (int*)  alloc((size_t)BB * NN * KK * 4);
    float* D_nb  = (float*)alloc((size_t)BB * NN * KK * 4);
    float* ADb   = (float*)alloc((size_t)BB * NN * 3 * 4);
    float* Ofb   = (float*)alloc((size_t)BB * NN * 9 * 4);
    float* hV    = (float*)alloc((size_t)BB * NN * HH * 4);
    unsigned short* hEbH = (unsigned short*)alloc((size_t)BB * NN * KK * HH * 2);
    float* Pb    = (float*)alloc((size_t)BB * NN * HH * 4);
    float* Qb    = (float*)alloc((size_t)BB * NN * HH * 4);
    float* sBuf  = (float*)alloc((size_t)BB * NN * HH * 4);
    float* cntB  = (float*)alloc((size_t)BB * NN * 4);
    short* WeP   = (short*)alloc(2 * 8192 * 2);
    short* WqP   = (short*)alloc(2 * 16384 * 2);
    short* W1bP  = (short*)alloc(3 * 2 * 16384 * 2);
    short* W2P   = (short*)alloc(3 * 2 * 16384 * 2);
    short* W3P   = (short*)alloc(3 * 2 * 16384 * 2);
    short* WiP   = (short*)alloc(3 * 2 * 65536 * 2);
    short* WoP   = (short*)alloc(3 * 2 * 65536 * 2);
    short* W1acP = (short*)alloc(3 * 2 * 32768 * 2);
    if (off > ws_size) return;

    pack_kernel<<<2592, 256, 0, stream>>>(We, Wq, lW1, lW2, lW3, lWi, lWo,
                                          WeP, WqP, W1bP, W2P, W3P, WiP, WoP, W1acP);
    knn_kernel<<<BB * NN / 4, 256, 0, stream>>>(X, mask, E_idx, D_nb);
    orient_kernel<<<(BB * NN + 255) / 256, 256, 0, stream>>>(X, ADb, Ofb);
    node_feat_kernel<<<BB * NN, HH, 0, stream>>>(ADb, Wn, bn, gn, hn, Wv, bv,
                                                 lW1, lb1, hV, Pb, Qb);
    edge_feat_kernel<<<BB * NN, HH, 0, stream>>>(X, E_idx, D_nb, Ofb,
                                                 be, ge, he, bq, WeP, WqP, hEbH);

    for (int l = 0; l < 3; l++) {
        int last = (l == 2);
        msg_kernel<<<BB * NN / 2, HH, 0, stream>>>(
            mask, E_idx, hEbH, Pb, Qb,
            W1bP + (size_t)l * 32768,
            W2P + (size_t)l * 32768, lb2 + (size_t)l * HH,
            sBuf, cntB);
        node_kernel<<<BB * NN / 16, 256, 0, stream>>>(
            mask, sBuf, cntB, hV,
            W3P + (size_t)l * 32768, lb3 + (size_t)l * HH,
            WiP + (size_t)l * 131072, lbi + (size_t)l * DFF,
            WoP + (size_t)l * 131072, lbo + (size_t)l * HH,
            lg0 + (size_t)l * HH, lh0 + (size_t)l * HH,
            lg1 + (size_t)l * HH, lh1 + (size_t)l * HH,
            last ? nullptr : (W1acP + (size_t)(l + 1) * 65536),
            last ? nullptr : (lb1 + (size_t)(l + 1) * HH),
            last ? (float*)d_out : hV,
            Pb, Qb);
    }
}

// Round 15
// 417.068 us; speedup vs baseline: 1.1300x; 1.0022x over previous
//
#include <hip/hip_runtime.h>
#include <math.h>

typedef __attribute__((ext_vector_type(8))) short short8;
typedef __attribute__((ext_vector_type(4))) float f32x4;

#define BB 2
#define NN 2048
#define KK 32
#define HH 128
#define DFF 512
#define EPSF 1e-6f
#define INFV 1e30f

#define MFMA16(a, b, c) __builtin_amdgcn_mfma_f32_16x16x32_bf16((a), (b), (c), 0, 0, 0)

// ---------- helpers ----------

__device__ __forceinline__ unsigned short f2bf(float f) {
    unsigned u = __float_as_uint(f);
    u += 0x7fffu + ((u >> 16) & 1u);          // round-to-nearest-even
    return (unsigned short)(u >> 16);
}

__device__ __forceinline__ float bf2f(unsigned short h) {
    return __uint_as_float(((unsigned)h) << 16);
}

// split x into hi+lo bf16 pair — WEIGHTS only (systematic error must stay split)
__device__ __forceinline__ void f2bf2(float x, short& hi, short& lo) {
    unsigned short h = f2bf(x);
    hi = (short)h;
    lo = (short)f2bf(x - bf2f(h));
}

// pack 8 floats -> hi-plane short8
__device__ __forceinline__ short8 cvt8h(f32x4 a, f32x4 b) {
    short8 h8;
    #pragma unroll
    for (int i = 0; i < 4; i++) h8[i] = (short)f2bf(a[i]);
    #pragma unroll
    for (int i = 0; i < 4; i++) h8[4 + i] = (short)f2bf(b[i]);
    return h8;
}

__device__ __forceinline__ float sgnf(float x) {
    return (x > 0.f) ? 1.f : ((x < 0.f) ? -1.f : 0.f);
}

__device__ __forceinline__ void norm3(float& x, float& y, float& z) {
    float n = sqrtf(x * x + y * y + z * z);
    n = fmaxf(n, 1e-12f);
    x /= n; y /= n; z /= n;
}

// block of 128 threads: sum over all threads, broadcast. 2 barriers.
__device__ __forceinline__ float blk2sum(float v, float* slots) {
    int lane = threadIdx.x & 63, wid = threadIdx.x >> 6;
    #pragma unroll
    for (int off = 32; off > 0; off >>= 1) v += __shfl_down(v, off);
    if (lane == 0) slots[wid] = v;
    __syncthreads();
    float r = slots[0] + slots[1];
    __syncthreads();
    return r;
}

// LN stats over 128 cols held in C-fragment layout (8 nt x f32x4)
__device__ __forceinline__ void lnC(const f32x4* vC, float* mu, float* inv) {
    float su[4] = {0, 0, 0, 0}, sq[4] = {0, 0, 0, 0};
    #pragma unroll
    for (int nt = 0; nt < 8; nt++)
        #pragma unroll
        for (int r = 0; r < 4; r++) { float v = vC[nt][r]; su[r] += v; sq[r] += v * v; }
    #pragma unroll
    for (int off = 1; off <= 8; off <<= 1)
        #pragma unroll
        for (int r = 0; r < 4; r++) { su[r] += __shfl_xor(su[r], off); sq[r] += __shfl_xor(sq[r], off); }
    #pragma unroll
    for (int r = 0; r < 4; r++) {
        mu[r] = su[r] * (1.f / HH);
        float var = (sq[r] - (float)HH * mu[r] * mu[r]) * (1.f / (HH - 1));
        inv[r] = 1.f / (sqrtf(var + EPSF) + EPSF);
    }
}

// ---------- kNN v5: 4 independent waves per block, ballot fast-path tiebreak ----------

__global__ __launch_bounds__(256) void knn_kernel(const float* __restrict__ X,
                                                  const float* __restrict__ mask,
                                                  int* __restrict__ E_idx,
                                                  float* __restrict__ D_nb) {
    int w = threadIdx.x >> 6, lane = threadIdx.x & 63;
    int g = blockIdx.x * 4 + w;
    int b = g >> 11, n = g & 2047;
    const float* Xb = X + (size_t)b * NN * 3;
    const float* mb = mask + (size_t)b * NN;

    float xn0 = Xb[n * 3], xn1 = Xb[n * 3 + 1], xn2 = Xb[n * 3 + 2];
    float mn = mb[n];

    float Dv[32], m2a[32];
    float lmax = -1e30f;
    #pragma unroll
    for (int s = 0; s < 32; s++) {
        int j = s * 64 + lane;
        float dx = Xb[j * 3] - xn0, dy = Xb[j * 3 + 1] - xn1, dz = Xb[j * 3 + 2] - xn2;
        float d = sqrtf(dx * dx + dy * dy + dz * dz + EPSF);
        float m2 = mn * mb[j];
        float v = m2 * d;
        Dv[s] = v; m2a[s] = m2;
        lmax = fmaxf(lmax, v);
    }
    #pragma unroll
    for (int off = 1; off <= 32; off <<= 1) lmax = fmaxf(lmax, __shfl_xor(lmax, off));
    float Dmax = lmax;
    #pragma unroll
    for (int s = 0; s < 32; s++) Dv[s] += (1.f - m2a[s]) * Dmax;

    // per-lane top-2 (strict < keeps earliest slot on exact ties)
    float l1 = INFV, l2 = INFV; int s1 = 0, s2 = 0;
    #pragma unroll
    for (int s = 0; s < 32; s++) {
        float v = Dv[s];
        bool lt1 = v < l1;
        bool lt2 = v < l2;
        float o1 = l1; int os1 = s1;
        l1 = lt1 ? v : l1;  s1 = lt1 ? s : s1;
        l2 = lt1 ? o1 : (lt2 ? v : l2);
        s2 = lt1 ? os1 : (lt2 ? s : s2);
    }

    unsigned used = 0u;
    float keepd = 0.f; int keepj = 0;

    for (int s = 0; s < KK; s++) {
        float m = l1;
        #pragma unroll
        for (int off = 1; off <= 32; off <<= 1) m = fminf(m, __shfl_xor(m, off));
        unsigned long long ball = __ballot(l1 == m);
        int jwin;
        if (__popcll(ball) == 1) {
            int src = (int)(__ffsll((long long)ball) - 1);
            jwin = __shfl(s1 * 64 + lane, src);
        } else {
            int jme = (l1 == m) ? (s1 * 64 + lane) : 0x7FFFFFFF;
            jwin = jme;
            #pragma unroll
            for (int off = 1; off <= 32; off <<= 1) jwin = min(jwin, __shfl_xor(jwin, off));
        }
        if (lane == s) { keepd = m; keepj = jwin; }
        if (lane == (jwin & 63)) {
            used |= 1u << s1;
            l1 = l2; s1 = s2;
            l2 = INFV;
            if (l1 >= INFV) {   // rare refill
                l1 = INFV; l2 = INFV;
                #pragma unroll
                for (int i = 0; i < 32; i++) {
                    float v = ((used >> i) & 1u) ? INFV : Dv[i];
                    bool lt1 = v < l1;
                    bool lt2 = v < l2;
                    float o1 = l1; int os1 = s1;
                    l1 = lt1 ? v : l1;  s1 = lt1 ? i : s1;
                    l2 = lt1 ? o1 : (lt2 ? v : l2);
                    s2 = lt1 ? os1 : (lt2 ? i : s2);
                }
            }
        }
    }
    if (lane < KK) {
        E_idx[(size_t)g * KK + lane] = keepj;
        D_nb[(size_t)g * KK + lane] = keepd;
    }
}

// ---------- weight pre-pack: fp32 -> (hi,lo) bf16 B-fragment planes ----------

__device__ __forceinline__ void packB(const float* __restrict__ src, short* __restrict__ dH,
                                      short* __restrict__ dL, int e, int KC, int N, int Kreal) {
    int j = e & 7, ln = (e >> 3) & 63, t = e >> 9;
    int kc = t % KC, nt = t / KC;
    int k = kc * 32 + (ln >> 4) * 8 + j;
    int n = nt * 16 + (ln & 15);
    float v = (k < Kreal) ? src[(size_t)k * N + n] : 0.f;
    short hi, lo; f2bf2(v, hi, lo);
    dH[e] = hi; dL[e] = lo;
}

__global__ __launch_bounds__(256) void pack_kernel(const float* __restrict__ We,
                                                   const float* __restrict__ Wq,
                                                   const float* __restrict__ lW1,
                                                   const float* __restrict__ lW2,
                                                   const float* __restrict__ lW3,
                                                   const float* __restrict__ lWi,
                                                   const float* __restrict__ lWo,
                                                   short* __restrict__ WeP,
                                                   short* __restrict__ WqP,
                                                   short* __restrict__ W1bP,
                                                   short* __restrict__ W2P,
                                                   short* __restrict__ W3P,
                                                   short* __restrict__ WiP,
                                                   short* __restrict__ WoP,
                                                   short* __restrict__ W1acP) {
    int e = blockIdx.x * 256 + threadIdx.x;
    if (e < 8192) { packB(We, WeP, WeP + 8192, e, 2, 128, 39); return; }
    e -= 8192;
    if (e < 16384) { packB(Wq, WqP, WqP + 16384, e, 4, 128, 128); return; }
    e -= 16384;
    if (e < 49152) {
        int l = e >> 14, r = e & 16383;
        packB(lW1 + (size_t)l * 49152 + 16384, W1bP + l * 32768, W1bP + l * 32768 + 16384, r, 4, 128, 128);
        return;
    }
    e -= 49152;
    if (e < 49152) {
        int l = e >> 14, r = e & 16383;
        packB(lW2 + (size_t)l * 16384, W2P + l * 32768, W2P + l * 32768 + 16384, r, 4, 128, 128);
        return;
    }
    e -= 49152;
    if (e < 49152) {
        int l = e >> 14, r = e & 16383;
        packB(lW3 + (size_t)l * 16384, W3P + l * 32768, W3P + l * 32768 + 16384, r, 4, 128, 128);
        return;
    }
    e -= 49152;
    if (e < 196608) {
        int l = e / 65536, r = e % 65536;
        packB(lWi + (size_t)l * 65536, WiP + l * 131072, WiP + l * 131072 + 65536, r, 4, 512, 128);
        return;
    }
    e -= 196608;
    if (e < 196608) {
        int l = e / 65536, r = e % 65536;
        packB(lWo + (size_t)l * 65536, WoP + l * 131072, WoP + l * 131072 + 65536, r, 16, 128, 512);
        return;
    }
    e -= 196608;
    if (e < 98304) {
        int l = e / 32768, r = e % 32768;
        int j = r & 7, ln = (r >> 3) & 63, t = r >> 9;
        int kc = t & 3, nt = t >> 2;
        int k = kc * 32 + (ln >> 4) * 8 + j;
        int n = nt * 16 + (ln & 15);
        const float* base = lW1 + (size_t)l * 49152;
        float v = (n < 128) ? base[(size_t)k * 128 + n] : base[(size_t)(256 + k) * 128 + (n - 128)];
        short hi, lo; f2bf2(v, hi, lo);
        short* dH = W1acP + l * 65536;
        dH[r] = hi; dH[32768 + r] = lo;
    }
}

// ---------- backbone frames ----------

__global__ void orient_kernel(const float* __restrict__ X,
                              float* __restrict__ AD,
                              float* __restrict__ Of) {
    int t = blockIdx.x * blockDim.x + threadIdx.x;
    if (t >= BB * NN) return;
    int b = t / NN, n = t % NN;
    float* ad = AD + (size_t)t * 3;
    float* of = Of + (size_t)t * 9;
    if (n < 1 || n > NN - 3) {
        ad[0] = ad[1] = ad[2] = 0.f;
        #pragma unroll
        for (int i = 0; i < 9; i++) of[i] = 0.f;
        return;
    }
    const float* Xb = X + (size_t)b * NN * 3;
    float p0x = Xb[(n - 1) * 3], p0y = Xb[(n - 1) * 3 + 1], p0z = Xb[(n - 1) * 3 + 2];
    float p1x = Xb[n * 3],       p1y = Xb[n * 3 + 1],       p1z = Xb[n * 3 + 2];
    float p2x = Xb[(n + 1) * 3], p2y = Xb[(n + 1) * 3 + 1], p2z = Xb[(n + 1) * 3 + 2];
    float p3x = Xb[(n + 2) * 3], p3y = Xb[(n + 2) * 3 + 1], p3z = Xb[(n + 2) * 3 + 2];

    float u2x = p1x - p0x, u2y = p1y - p0y, u2z = p1z - p0z; norm3(u2x, u2y, u2z);
    float u1x = p2x - p1x, u1y = p2y - p1y, u1z = p2z - p1z; norm3(u1x, u1y, u1z);
    float u0x = p3x - p2x, u0y = p3y - p2y, u0z = p3z - p2z; norm3(u0x, u0y, u0z);

    float n2x = u2y * u1z - u2z * u1y, n2y = u2z * u1x - u2x * u1z, n2z = u2x * u1y - u2y * u1x;
    norm3(n2x, n2y, n2z);
    float n1x = u1y * u0z - u1z * u0y, n1y = u1z * u0x - u1x * u0z, n1z = u1x * u0y - u1y * u0x;
    norm3(n1x, n1y, n1z);

    float cosA = -(u1x * u0x + u1y * u0y + u1z * u0z);
    cosA = fminf(fmaxf(cosA, -1.f + EPSF), 1.f - EPSF);
    float A = acosf(cosA);
    float cosD = n2x * n1x + n2y * n1y + n2z * n1z;
    cosD = fminf(fmaxf(cosD, -1.f + EPSF), 1.f - EPSF);
    float sg = sgnf(u2x * n1x + u2y * n1y + u2z * n1z);
    float Dih = sg * acosf(cosD);

    ad[0] = cosf(A);
    ad[1] = sinf(A) * cosf(Dih);
    ad[2] = sinf(A) * sinf(Dih);

    float o1x = u2x - u1x, o1y = u2y - u1y, o1z = u2z - u1z; norm3(o1x, o1y, o1z);
    float cx = o1y * n2z - o1z * n2y, cy = o1z * n2x - o1x * n2z, cz = o1x * n2y - o1y * n2x;
    of[0] = o1x; of[1] = o1y; of[2] = o1z;
    of[3] = n2x; of[4] = n2y; of[5] = n2z;
    of[6] = cx;  of[7] = cy;  of[8] = cz;
}

// ---------- node features + premix for layer 0 (fp32) ----------

__global__ __launch_bounds__(128) void node_feat_kernel(const float* __restrict__ AD,
                                                        const float* __restrict__ Wn,
                                                        const float* __restrict__ bn,
                                                        const float* __restrict__ gn,
                                                        const float* __restrict__ hn,
                                                        const float* __restrict__ Wv,
                                                        const float* __restrict__ bv,
                                                        const float* __restrict__ W1_0,
                                                        const float* __restrict__ b1_0,
                                                        float* __restrict__ hV,
                                                        float* __restrict__ P,
                                                        float* __restrict__ Q) {
    __shared__ __align__(16) float y[HH];
    __shared__ float slots[2];
    int n = blockIdx.x; int h = threadIdx.x;
    float a0 = AD[n * 3], a1 = AD[n * 3 + 1], a2 = AD[n * 3 + 2];
    float v = bn[h] + a0 * Wn[h] + a1 * Wn[HH + h] + a2 * Wn[2 * HH + h];
    float mu = blk2sum(v, slots) * (1.f / HH);
    float d = v - mu;
    float var = blk2sum(d * d, slots) * (1.f / (HH - 1));
    float yv = gn[h] * d / (sqrtf(var + EPSF) + EPSF) + hn[h];
    y[h] = yv; __syncthreads();
    float acc = bv[h];
    for (int c4 = 0; c4 < 32; c4++) {
        f32x4 v4 = ((const f32x4*)y)[c4]; int c = 4 * c4;
        acc += v4.x * Wv[c * HH + h] + v4.y * Wv[(c + 1) * HH + h]
             + v4.z * Wv[(c + 2) * HH + h] + v4.w * Wv[(c + 3) * HH + h];
    }
    hV[(size_t)n * HH + h] = acc;
    __syncthreads(); y[h] = acc; __syncthreads();
    float p = b1_0[h], qv = 0.f;
    for (int c4 = 0; c4 < 32; c4++) {
        f32x4 v4 = ((const f32x4*)y)[c4]; int c = 4 * c4;
        p  += v4.x * W1_0[c * HH + h]        + v4.y * W1_0[(c + 1) * HH + h]
            + v4.z * W1_0[(c + 2) * HH + h]  + v4.w * W1_0[(c + 3) * HH + h];
        qv += v4.x * W1_0[(256 + c) * HH + h]       + v4.y * W1_0[(256 + c + 1) * HH + h]
            + v4.z * W1_0[(256 + c + 2) * HH + h]   + v4.w * W1_0[(256 + c + 3) * HH + h];
    }
    P[(size_t)n * HH + h] = p;
    Q[(size_t)n * HH + h] = qv;
}

// ---------- edge features: A-side hi-only, B-side split; fast transcendentals ----------

__global__ __launch_bounds__(128) void edge_feat_kernel(const float* __restrict__ X,
                                                        const int* __restrict__ E_idx,
                                                        const float* __restrict__ D_nb,
                                                        const float* __restrict__ Of,
                                                        const float* __restrict__ be,
                                                        const float* __restrict__ ge,
                                                        const float* __restrict__ he,
                                                        const float* __restrict__ bq,
                                                        const short* __restrict__ WeP,
                                                        const short* __restrict__ WqP,
                                                        unsigned short* __restrict__ hEbH) {
    __shared__ short AefH[32 * 72];
    __shared__ short AeH[32 * 136];
    __shared__ float beS[HH], geS[HH], heS[HH], bqS[HH];

    int bid = blockIdx.x; int b = bid >> 11, n = bid & 2047; int tid = threadIdx.x;
    int lane = tid & 63, w = tid >> 6;
    beS[tid] = be[tid]; geS[tid] = ge[tid]; heS[tid] = he[tid]; bqS[tid] = bq[tid];
    {
        unsigned* Az = (unsigned*)AefH;
        for (int i = tid; i < 32 * 72 / 2; i += 128) Az[i] = 0u;
    }
    __syncthreads();

    int part = tid >> 5, k = tid & 31;
    int e = E_idx[(size_t)bid * KK + k];
    float dpos = (float)e - (float)n;
    if (part == 1 || part == 2) {
        int p0 = (part - 1) * 4;
        #pragma unroll
        for (int p = 0; p < 4; p++) {
            float fr = expf((float)(2 * (p0 + p)) * -0.5756462732485115f);  // compile-time folded
            float ang = dpos * fr;
            AefH[k * 72 + p0 + p]     = (short)f2bf(__cosf(ang));
            AefH[k * 72 + 8 + p0 + p] = (short)f2bf(__sinf(ang));
        }
    } else if (part == 3) {
        float Dv = D_nb[(size_t)bid * KK + k];
        #pragma unroll
        for (int i = 0; i < 16; i++) {
            float m = (20.f / 15.f) * (float)i;
            float z = (Dv - m) * 0.8f;
            AefH[k * 72 + 16 + i] = (short)f2bf(__expf(-z * z));
        }
    } else {
        const float* Omp = Of + (size_t)(b * NN + n) * 9;
        const float* Onp = Of + (size_t)(b * NN + e) * 9;
        float Om[9], On[9];
        #pragma unroll
        for (int i = 0; i < 9; i++) { Om[i] = Omp[i]; On[i] = Onp[i]; }
        float vx = X[(size_t)(b * NN + e) * 3 + 0] - X[(size_t)(b * NN + n) * 3 + 0];
        float vy = X[(size_t)(b * NN + e) * 3 + 1] - X[(size_t)(b * NN + n) * 3 + 1];
        float vz = X[(size_t)(b * NN + e) * 3 + 2] - X[(size_t)(b * NN + n) * 3 + 2];
        float t0 = Om[0] * vx + Om[1] * vy + Om[2] * vz;
        float t1 = Om[3] * vx + Om[4] * vy + Om[5] * vz;
        float t2 = Om[6] * vx + Om[7] * vy + Om[8] * vz;
        float nr = fmaxf(sqrtf(t0 * t0 + t1 * t1 + t2 * t2), 1e-12f);
        AefH[k * 72 + 32] = (short)f2bf(t0 / nr);
        AefH[k * 72 + 33] = (short)f2bf(t1 / nr);
        AefH[k * 72 + 34] = (short)f2bf(t2 / nr);
        float R[9];
        #pragma unroll
        for (int i = 0; i < 3; i++)
            #pragma unroll
            for (int l = 0; l < 3; l++)
                R[i * 3 + l] = Om[0 + i] * On[0 + l] + Om[3 + i] * On[3 + l] + Om[6 + i] * On[6 + l];
        float Rxx = R[0], Ryy = R[4], Rzz = R[8];
        float mx = 0.5f * sqrtf(fabsf(1.f + Rxx - Ryy - Rzz));
        float my = 0.5f * sqrtf(fabsf(1.f - Rxx + Ryy - Rzz));
        float mz = 0.5f * sqrtf(fabsf(1.f - Rxx - Ryy + Rzz));
        float qx = sgnf(R[7] - R[5]) * mx;
        float qy = sgnf(R[2] - R[6]) * my;
        float qz = sgnf(R[3] - R[1]) * mz;
        float qw = 0.5f * sqrtf(fmaxf(1.f + Rxx + Ryy + Rzz, 0.f));
        float qn = fmaxf(sqrtf(qx * qx + qy * qy + qz * qz + qw * qw), 1e-12f);
        AefH[k * 72 + 35] = (short)f2bf(qx / qn);
        AefH[k * 72 + 36] = (short)f2bf(qy / qn);
        AefH[k * 72 + 37] = (short)f2bf(qz / qn);
        AefH[k * 72 + 38] = (short)f2bf(qw / qn);
    }
    __syncthreads();

    int m = lane & 15, q = lane >> 4;
    int row = (w * 16 + m) * 72;
    short8 a0h = *(const short8*)&AefH[row + q * 8];
    short8 a1h = *(const short8*)&AefH[row + 32 + q * 8];
    f32x4 accA[8];
    #pragma unroll
    for (int nt = 0; nt < 8; nt++) {
        float bc = beS[nt * 16 + m];
        f32x4 acc = {bc, bc, bc, bc};
        const short* B0 = &WeP[((nt * 2 + 0) * 64 + lane) * 8];
        const short* B1 = &WeP[((nt * 2 + 1) * 64 + lane) * 8];
        short8 b0h = *(const short8*)B0, b0l = *(const short8*)(B0 + 8192);
        short8 b1h = *(const short8*)B1, b1l = *(const short8*)(B1 + 8192);
        acc = MFMA16(a0h, b0h, acc);
        acc = MFMA16(a0h, b0l, acc);
        acc = MFMA16(a1h, b1h, acc);
        acc = MFMA16(a1h, b1l, acc);
        accA[nt] = acc;
    }
    float mu[4], inv[4];
    lnC(accA, mu, inv);
    #pragma unroll
    for (int nt = 0; nt < 8; nt++) {
        int col = nt * 16 + m;
        float g = geS[col], hh = heS[col];
        #pragma unroll
        for (int r = 0; r < 4; r++) {
            int edge = w * 16 + q * 4 + r;
            float y = g * (accA[nt][r] - mu[r]) * inv[r] + hh;
            AeH[edge * 136 + col] = (short)f2bf(y);
        }
    }
    __syncthreads();

    short8 ah[4];
    #pragma unroll
    for (int kc = 0; kc < 4; kc++)
        ah[kc] = *(const short8*)&AeH[(w * 16 + m) * 136 + kc * 32 + q * 8];
    #pragma unroll
    for (int nt = 0; nt < 8; nt++) {
        int col = nt * 16 + m;
        float bc = bqS[col];
        f32x4 acc = {bc, bc, bc, bc};
        #pragma unroll
        for (int kc = 0; kc < 4; kc++) {
            const short* Bp = &WqP[((nt * 4 + kc) * 64 + lane) * 8];
            short8 bh = *(const short8*)Bp, bl = *(const short8*)(Bp + 16384);
            acc = MFMA16(ah[kc], bh, acc);
            acc = MFMA16(ah[kc], bl, acc);
        }
        #pragma unroll
        for (int r = 0; r < 4; r++) {
            int edge = w * 16 + q * 4 + r;
            hEbH[(size_t)bid * (KK * HH) + edge * HH + col] = f2bf(acc[r]);
        }
    }
}

// ---------- message kernel v6: one node per wave, all A-sides hi-only ----------

__global__ __launch_bounds__(128, 2) void msg_kernel(const float* __restrict__ mask,
                                                     const int* __restrict__ E_idx,
                                                     const unsigned short* __restrict__ hEbH,
                                                     const float* __restrict__ P,
                                                     const float* __restrict__ Q,
                                                     const short* __restrict__ W1bP,
                                                     const short* __restrict__ W2P,
                                                     const float* __restrict__ b2,
                                                     float* __restrict__ sOut,
                                                     float* __restrict__ cntOut) {
    __shared__ short AmH[2][32 * 136];

    int w = threadIdx.x >> 6, lane = threadIdx.x & 63;
    int g = blockIdx.x * 2 + w;          // node id
    int b = g >> 11;
    int m = lane & 15, q = lane >> 4;

    float maskv = mask[g];
    int erow[2][4]; float mt[2][4];
    #pragma unroll
    for (int t = 0; t < 2; t++)
        #pragma unroll
        for (int r = 0; r < 4; r++) {
            int row = t * 16 + q * 4 + r;
            erow[t][r] = E_idx[(size_t)g * KK + row];
            mt[t][r] = maskv * mask[b * NN + erow[t][r]];
        }
    {
        float c8 = mt[0][0] + mt[0][1] + mt[0][2] + mt[0][3]
                 + mt[1][0] + mt[1][1] + mt[1][2] + mt[1][3];
        c8 += __shfl_xor(c8, 16);
        c8 += __shfl_xor(c8, 32);
        if (lane == 0) cntOut[g] = c8;
    }

    float preg[8], b2reg[8];
    float qreg[8][2][4];
    #pragma unroll
    for (int nt = 0; nt < 8; nt++) {
        preg[nt]  = P[(size_t)g * HH + nt * 16 + m];
        b2reg[nt] = b2[nt * 16 + m];
        #pragma unroll
        for (int t = 0; t < 2; t++)
            #pragma unroll
            for (int r = 0; r < 4; r++)
                qreg[nt][t][r] = Q[((size_t)b * NN + erow[t][r]) * HH + nt * 16 + m];
    }

    // phase 1: m1 = relu(P + Q[nbr] + h_E @ W1b)
    {
        const unsigned short* hbH = hEbH + (size_t)g * (KK * HH);
        short8 aheH[2][4];
        #pragma unroll
        for (int t = 0; t < 2; t++)
            #pragma unroll
            for (int kc = 0; kc < 4; kc++)
                aheH[t][kc] = *(const short8*)(hbH + (t * 16 + m) * HH + kc * 32 + q * 8);
        #pragma unroll
        for (int nt = 0; nt < 8; nt++) {
            f32x4 t0 = {0.f, 0.f, 0.f, 0.f}, t1 = {0.f, 0.f, 0.f, 0.f};
            #pragma unroll
            for (int kc = 0; kc < 4; kc++) {
                const short* Bp = &W1bP[((nt * 4 + kc) * 64 + lane) * 8];
                short8 bh = *(const short8*)Bp, bl = *(const short8*)(Bp + 16384);
                t0 = MFMA16(aheH[0][kc], bh, t0);
                t0 = MFMA16(aheH[0][kc], bl, t0);
                t1 = MFMA16(aheH[1][kc], bh, t1);
                t1 = MFMA16(aheH[1][kc], bl, t1);
            }
            int col = nt * 16 + m;
            float pp = preg[nt];
            #pragma unroll
            for (int r = 0; r < 4; r++) {
                float v0 = fmaxf(t0[r] + pp + qreg[nt][0][r], 0.f);
                AmH[w][(q * 4 + r) * 136 + col] = (short)f2bf(v0);
                float v1 = fmaxf(t1[r] + pp + qreg[nt][1][r], 0.f);
                AmH[w][(16 + q * 4 + r) * 136 + col] = (short)f2bf(v1);
            }
        }
    }
    __syncthreads();

    // phase 2: m2 = relu(m1 @ W2 + b2); masked sum over 32 edges
    {
        short8 amh[2][4];
        #pragma unroll
        for (int t = 0; t < 2; t++)
            #pragma unroll
            for (int kc = 0; kc < 4; kc++)
                amh[t][kc] = *(const short8*)&AmH[w][(t * 16 + m) * 136 + kc * 32 + q * 8];
        #pragma unroll
        for (int nt = 0; nt < 8; nt++) {
            float bc = b2reg[nt];
            f32x4 a0 = {bc, bc, bc, bc}, a1 = {bc, bc, bc, bc};
            #pragma unroll
            for (int kc = 0; kc < 4; kc++) {
                const short* Bp = &W2P[((nt * 4 + kc) * 64 + lane) * 8];
                short8 bh = *(const short8*)Bp, bl = *(const short8*)(Bp + 16384);
                a0 = MFMA16(amh[0][kc], bh, a0);
                a0 = MFMA16(amh[0][kc], bl, a0);
                a1 = MFMA16(amh[1][kc], bh, a1);
                a1 = MFMA16(amh[1][kc], bl, a1);
            }
            float part = 0.f;
            #pragma unroll
            for (int r = 0; r < 4; r++)
                part += fmaxf(a0[r], 0.f) * mt[0][r] + fmaxf(a1[r], 0.f) * mt[1][r];
            part += __shfl_xor(part, 16);
            part += __shfl_xor(part, 32);
            if (q == 0) sOut[(size_t)g * HH + nt * 16 + m] = part;
        }
    }
}

// ---------- node kernel: 4 waves, A-sides hi-only ----------

#define HSTR 520   // LDS stride (shorts) for 512-wide hidden staging

__global__ __launch_bounds__(256, 3) void node_kernel(const float* __restrict__ mask,
                                                      const float* __restrict__ sbuf,
                                                      const float* __restrict__ cntb,
                                                      const float* __restrict__ hVin,
                                                      const short* __restrict__ W3P,
                                                      const float* __restrict__ b3,
                                                      const short* __restrict__ WiP,
                                                      const float* __restrict__ biN,
                                                      const short* __restrict__ WoP,
                                                      const float* __restrict__ boN,
                                                      const float* __restrict__ g0,
                                                      const float* __restrict__ h0,
                                                      const float* __restrict__ g1,
                                                      const float* __restrict__ h1,
                                                      const short* __restrict__ W1P,
                                                      const float* __restrict__ b1n,
                                                      float* __restrict__ hVout,
                                                      float* __restrict__ Pn,
                                                      float* __restrict__ Qn) {
    __shared__ short rbH[16 * 136];
    __shared__ short hbH[16 * HSTR];
    __shared__ float redS[4][2][16];
    __shared__ float g0S[128], h0S[128], g1S[128], h1S[128], b3S[128], boS[128], b1S[128];
    __shared__ float biS[512];

    int tid = threadIdx.x;
    int w = tid >> 6, lane = tid & 63;
    int m = lane & 15, q = lane >> 4;
    int rowT = blockIdx.x * 16;

    for (int i = tid; i < 128; i += 256) {
        g0S[i] = g0[i]; h0S[i] = h0[i]; g1S[i] = g1[i]; h1S[i] = h1[i];
        b3S[i] = b3[i]; boS[i] = boN[i]; b1S[i] = W1P ? b1n[i] : 0.f;
    }
    for (int i = tid; i < 512; i += 256) biS[i] = biN[i];
    __syncthreads();

    short8 ash[4];
    #pragma unroll
    for (int kc = 0; kc < 4; kc++) {
        const float* sp = &sbuf[(size_t)(rowT + m) * HH + kc * 32 + q * 8];
        f32x4 x0 = *(const f32x4*)sp;
        f32x4 x1 = *(const f32x4*)(sp + 4);
        ash[kc] = cvt8h(x0, x1);
    }
    float cntr[4];
    #pragma unroll
    for (int r = 0; r < 4; r++) cntr[r] = cntb[rowT + q * 4 + r];

    f32x4 vC2[2];
    #pragma unroll
    for (int t = 0; t < 2; t++) {
        int nt = 2 * w + t;
        f32x4 a = {0.f, 0.f, 0.f, 0.f};
        #pragma unroll
        for (int kc = 0; kc < 4; kc++) {
            const short* Bp = &W3P[((nt * 4 + kc) * 64 + lane) * 8];
            short8 bh = *(const short8*)Bp, bl = *(const short8*)(Bp + 16384);
            a = MFMA16(ash[kc], bh, a);
            a = MFMA16(ash[kc], bl, a);
        }
        int col = nt * 16 + m;
        #pragma unroll
        for (int r = 0; r < 4; r++) {
            float tv = (a[r] + cntr[r] * b3S[col]) * (1.f / 30.f);
            a[r] = hVin[(size_t)(rowT + q * 4 + r) * HH + col] + tv;
        }
        vC2[t] = a;
    }

    // LN0 (cross-wave)
    {
        float su[4] = {0, 0, 0, 0}, sq[4] = {0, 0, 0, 0};
        #pragma unroll
        for (int t = 0; t < 2; t++)
            #pragma unroll
            for (int r = 0; r < 4; r++) { float v = vC2[t][r]; su[r] += v; sq[r] += v * v; }
        #pragma unroll
        for (int off = 1; off <= 8; off <<= 1)
            #pragma unroll
            for (int r = 0; r < 4; r++) { su[r] += __shfl_xor(su[r], off); sq[r] += __shfl_xor(sq[r], off); }
        if (m == 0) {
            #pragma unroll
            for (int r = 0; r < 4; r++) { redS[w][0][q * 4 + r] = su[r]; redS[w][1][q * 4 + r] = sq[r]; }
        }
    }
    __syncthreads();
    float mu[4], inv[4];
    #pragma unroll
    for (int r = 0; r < 4; r++) {
        int row = q * 4 + r;
        float S  = redS[0][0][row] + redS[1][0][row] + redS[2][0][row] + redS[3][0][row];
        float Q2 = redS[0][1][row] + redS[1][1][row] + redS[2][1][row] + redS[3][1][row];
        mu[r] = S * (1.f / HH);
        float var = (Q2 - (float)HH * mu[r] * mu[r]) * (1.f / (HH - 1));
        inv[r] = 1.f / (sqrtf(var + EPSF) + EPSF);
    }
    #pragma unroll
    for (int t = 0; t < 2; t++) {
        int col = (2 * w + t) * 16 + m;
        #pragma unroll
        for (int r = 0; r < 4; r++)
            vC2[t][r] = g0S[col] * (vC2[t][r] - mu[r]) * inv[r] + h0S[col];
    }
    #pragma unroll
    for (int t = 0; t < 2; t++) {
        int col = (2 * w + t) * 16 + m;
        #pragma unroll
        for (int r = 0; r < 4; r++)
            rbH[(q * 4 + r) * 136 + col] = (short)f2bf(vC2[t][r]);
    }
    __syncthreads();

    short8 avh[4];
    #pragma unroll
    for (int kc = 0; kc < 4; kc++)
        avh[kc] = *(const short8*)&rbH[m * 136 + kc * 32 + q * 8];

    // FFN-in: wave's 128 hidden cols
    #pragma unroll
    for (int nt2 = 0; nt2 < 8; nt2++) {
        int jcol = w * 128 + nt2 * 16 + m;
        float bb = biS[jcol];
        f32x4 a = {bb, bb, bb, bb};
        #pragma unroll
        for (int kc = 0; kc < 4; kc++) {
            const short* Bp = &WiP[(((w * 8 + nt2) * 4 + kc) * 64 + lane) * 8];
            short8 bh = *(const short8*)Bp, bl = *(const short8*)(Bp + 65536);
            a = MFMA16(avh[kc], bh, a);
            a = MFMA16(avh[kc], bl, a);
        }
        #pragma unroll
        for (int r = 0; r < 4; r++)
            hbH[(q * 4 + r) * HSTR + jcol] = (short)f2bf(fmaxf(a[r], 0.f));
    }
    __syncthreads();

    // FFN-out: wave's 2 col-tiles over ALL 512 hidden
    f32x4 oC2[2] = {{0.f, 0.f, 0.f, 0.f}, {0.f, 0.f, 0.f, 0.f}};
    for (int kc2 = 0; kc2 < 16; kc2++) {
        short8 ahh = *(const short8*)&hbH[m * HSTR + kc2 * 32 + q * 8];
        #pragma unroll
        for (int t = 0; t < 2; t++) {
            int nt = 2 * w + t;
            const short* Bp = &WoP[((nt * 16 + kc2) * 64 + lane) * 8];
            short8 bh = *(const short8*)Bp, bl = *(const short8*)(Bp + 65536);
            oC2[t] = MFMA16(ahh, bh, oC2[t]);
            oC2[t] = MFMA16(ahh, bl, oC2[t]);
        }
    }
    #pragma unroll
    for (int t = 0; t < 2; t++) {
        int col = (2 * w + t) * 16 + m;
        #pragma unroll
        for (int r = 0; r < 4; r++)
            oC2[t][r] += boS[col] + vC2[t][r];
    }

    // LN1 (cross-wave)
    {
        float su[4] = {0, 0, 0, 0}, sq[4] = {0, 0, 0, 0};
        #pragma unroll
        for (int t = 0; t < 2; t++)
            #pragma unroll
            for (int r = 0; r < 4; r++) { float v = oC2[t][r]; su[r] += v; sq[r] += v * v; }
        #pragma unroll
        for (int off = 1; off <= 8; off <<= 1)
            #pragma unroll
            for (int r = 0; r < 4; r++) { su[r] += __shfl_xor(su[r], off); sq[r] += __shfl_xor(sq[r], off); }
        __syncthreads();   // redS reuse
        if (m == 0) {
            #pragma unroll
            for (int r = 0; r < 4; r++) { redS[w][0][q * 4 + r] = su[r]; redS[w][1][q * 4 + r] = sq[r]; }
        }
    }
    __syncthreads();
    #pragma unroll
    for (int r = 0; r < 4; r++) {
        int row = q * 4 + r;
        float S  = redS[0][0][row] + redS[1][0][row] + redS[2][0][row] + redS[3][0][row];
        float Q2 = redS[0][1][row] + redS[1][1][row] + redS[2][1][row] + redS[3][1][row];
        mu[r] = S * (1.f / HH);
        float var = (Q2 - (float)HH * mu[r] * mu[r]) * (1.f / (HH - 1));
        inv[r] = 1.f / (sqrtf(var + EPSF) + EPSF);
    }
    float mk[4];
    #pragma unroll
    for (int r = 0; r < 4; r++) mk[r] = mask[rowT + q * 4 + r];
    #pragma unroll
    for (int t = 0; t < 2; t++) {
        int col = (2 * w + t) * 16 + m;
        #pragma unroll
        for (int r = 0; r < 4; r++) {
            float y = g1S[col] * (oC2[t][r] - mu[r]) * inv[r] + h1S[col];
            y *= mk[r];
            oC2[t][r] = y;
            hVout[(size_t)(rowT + q * 4 + r) * HH + col] = y;
        }
    }

    // fused next-layer premix (wave's 4 of 16 col-tiles)
    if (W1P) {
        __syncthreads();
        #pragma unroll
        for (int t = 0; t < 2; t++) {
            int col = (2 * w + t) * 16 + m;
            #pragma unroll
            for (int r = 0; r < 4; r++)
                rbH[(q * 4 + r) * 136 + col] = (short)f2bf(oC2[t][r]);
        }
        __syncthreads();
        short8 ayh[4];
        #pragma unroll
        for (int kc = 0; kc < 4; kc++)
            ayh[kc] = *(const short8*)&rbH[m * 136 + kc * 32 + q * 8];
        #pragma unroll
        for (int u = 0; u < 4; u++) {
            int nt = w * 4 + u;
            int col = nt * 16 + m;
            float b0 = (nt < 8) ? b1S[col] : 0.f;
            f32x4 a = {b0, b0, b0, b0};
            #pragma unroll
            for (int kc = 0; kc < 4; kc++) {
                const short* Bp = &W1P[((nt * 4 + kc) * 64 + lane) * 8];
                short8 bh = *(const short8*)Bp, bl = *(const short8*)(Bp + 32768);
                a = MFMA16(ayh[kc], bh, a);
                a = MFMA16(ayh[kc], bl, a);
            }
            #pragma unroll
            for (int r = 0; r < 4; r++) {
                size_t row = rowT + q * 4 + r;
                if (nt < 8) Pn[row * HH + col] = a[r];
                else        Qn[row * HH + (col - 128)] = a[r];
            }
        }
    }
}

// ---------- launch ----------

extern "C" void kernel_launch(void* const* d_in, const int* in_sizes, int n_in,
                              void* d_out, int out_size, void* d_ws, size_t ws_size,
                              hipStream_t stream) {
    const float* X    = (const float*)d_in[0];
    const float* mask = (const float*)d_in[1];
    const float* Wn   = (const float*)d_in[2];
    const float* bn   = (const float*)d_in[3];
    const float* gn   = (const float*)d_in[4];
    const float* hn   = (const float*)d_in[5];
    const float* We   = (const float*)d_in[6];
    const float* be   = (const float*)d_in[7];
    const float* ge   = (const float*)d_in[8];
    const float* he   = (const float*)d_in[9];
    const float* Wv   = (const float*)d_in[10];
    const float* bv   = (const float*)d_in[11];
    const float* Wq   = (const float*)d_in[12];
    const float* bq   = (const float*)d_in[13];
    const float* lW1  = (const float*)d_in[14];
    const float* lb1  = (const float*)d_in[15];
    const float* lW2  = (const float*)d_in[16];
    const float* lb2  = (const float*)d_in[17];
    const float* lW3  = (const float*)d_in[18];
    const float* lb3  = (const float*)d_in[19];
    const float* lWi  = (const float*)d_in[20];
    const float* lbi  = (const float*)d_in[21];
    const float* lWo  = (const float*)d_in[22];
    const float* lbo  = (const float*)d_in[23];
    const float* lg0  = (const float*)d_in[24];
    const float* lh0  = (const float*)d_in[25];
    const float* lg1  = (const float*)d_in[26];
    const float* lh1  = (const float*)d_in[27];

    char* ws = (char*)d_ws;
    size_t off = 0;
    auto alloc = [&](size_t nbytes) { void* p = ws + off; off += (nbytes + 15) & ~(size_t)15; return p; };
    int*   E_idx = (int*)  alloc((size_t)BB * NN * KK * 4);
    float* D_nb  = (float*)alloc((size_t)BB * NN * KK * 4);
    float* ADb   = (float*)alloc((size_t)BB * NN * 3 * 4);
    float* Ofb   = (float*)alloc((size_t)BB * NN * 9 * 4);
    float* hV    = (float*)alloc((size_t)BB * NN * HH * 4);
    unsigned short* hEbH = (unsigned short*)alloc((size_t)BB * NN * KK * HH * 2);
    float* Pb    = (float*)alloc((size_t)BB * NN * HH * 4);
    float* Qb    = (float*)alloc((size_t)BB * NN * HH * 4);
    float* sBuf  = (float*)alloc((size_t)BB * NN * HH * 4);
    float* cntB  = (float*)alloc((size_t)BB * NN * 4);
    short* WeP   = (short*)alloc(2 * 8192 * 2);
    short* WqP   = (short*)alloc(2 * 16384 * 2);
    short* W1bP  = (short*)alloc(3 * 2 * 16384 * 2);
    short* W2P   = (short*)alloc(3 * 2 * 16384 * 2);
    short* W3P   = (short*)alloc(3 * 2 * 16384 * 2);
    short* WiP   = (short*)alloc(3 * 2 * 65536 * 2);
    short* WoP   = (short*)alloc(3 * 2 * 65536 * 2);
    short* W1acP = (short*)alloc(3 * 2 * 32768 * 2);
    if (off > ws_size) return;

    pack_kernel<<<2592, 256, 0, stream>>>(We, Wq, lW1, lW2, lW3, lWi, lWo,
                                          WeP, WqP, W1bP, W2P, W3P, WiP, WoP, W1acP);
    knn_kernel<<<BB * NN / 4, 256, 0, stream>>>(X, mask, E_idx, D_nb);
    orient_kernel<<<(BB * NN + 255) / 256, 256, 0, stream>>>(X, ADb, Ofb);
    node_feat_kernel<<<BB * NN, HH, 0, stream>>>(ADb, Wn, bn, gn, hn, Wv, bv,
                                                 lW1, lb1, hV, Pb, Qb);
    edge_feat_kernel<<<BB * NN, HH, 0, stream>>>(X, E_idx, D_nb, Ofb,
                                                 be, ge, he, bq, WeP, WqP, hEbH);

    for (int l = 0; l < 3; l++) {
        int last = (l == 2);
        msg_kernel<<<BB * NN / 2, HH, 0, stream>>>(
            mask, E_idx, hEbH, Pb, Qb,
            W1bP + (size_t)l * 32768,
            W2P + (size_t)l * 32768, lb2 + (size_t)l * HH,
            sBuf, cntB);
        node_kernel<<<BB * NN / 16, 256, 0, stream>>>(
            mask, sBuf, cntB, hV,
            W3P + (size_t)l * 32768, lb3 + (size_t)l * HH,
            WiP + (size_t)l * 131072, lbi + (size_t)l * DFF,
            WoP + (size_t)l * 131072, lbo + (size_t)l * HH,
            lg0 + (size_t)l * HH, lh0 + (size_t)l * HH,
            lg1 + (size_t)l * HH, lh1 + (size_t)l * HH,
            last ? nullptr : (W1acP + (size_t)(l + 1) * 65536),
            last ? nullptr : (lb1 + (size_t)(l + 1) * HH),
            last ? (float*)d_out : hV,
            Pb, Qb);
    }
}

// Round 16
// 400.347 us; speedup vs baseline: 1.1772x; 1.0418x over previous
//
#include <hip/hip_runtime.h>
#include <math.h>

typedef __attribute__((ext_vector_type(8))) short short8;
typedef __attribute__((ext_vector_type(4))) float f32x4;

#define BB 2
#define NN 2048
#define KK 32
#define HH 128
#define DFF 512
#define EPSF 1e-6f
#define INFV 1e30f

#define KNN_BLK 1024
#define PACK_BLK 2592
#define ORIENT_BLK 16

#define MFMA16(a, b, c) __builtin_amdgcn_mfma_f32_16x16x32_bf16((a), (b), (c), 0, 0, 0)

// ---------- helpers ----------

__device__ __forceinline__ unsigned short f2bf(float f) {
    unsigned u = __float_as_uint(f);
    u += 0x7fffu + ((u >> 16) & 1u);          // round-to-nearest-even
    return (unsigned short)(u >> 16);
}

__device__ __forceinline__ float bf2f(unsigned short h) {
    return __uint_as_float(((unsigned)h) << 16);
}

// split x into hi+lo bf16 pair — WEIGHTS only (systematic error must stay split)
__device__ __forceinline__ void f2bf2(float x, short& hi, short& lo) {
    unsigned short h = f2bf(x);
    hi = (short)h;
    lo = (short)f2bf(x - bf2f(h));
}

// pack 8 floats -> hi-plane short8
__device__ __forceinline__ short8 cvt8h(f32x4 a, f32x4 b) {
    short8 h8;
    #pragma unroll
    for (int i = 0; i < 4; i++) h8[i] = (short)f2bf(a[i]);
    #pragma unroll
    for (int i = 0; i < 4; i++) h8[4 + i] = (short)f2bf(b[i]);
    return h8;
}

__device__ __forceinline__ float sgnf(float x) {
    return (x > 0.f) ? 1.f : ((x < 0.f) ? -1.f : 0.f);
}

__device__ __forceinline__ void norm3(float& x, float& y, float& z) {
    float n = sqrtf(x * x + y * y + z * z);
    n = fmaxf(n, 1e-12f);
    x /= n; y /= n; z /= n;
}

// block of 128 threads: sum over all threads, broadcast. 2 barriers.
__device__ __forceinline__ float blk2sum(float v, float* slots) {
    int lane = threadIdx.x & 63, wid = threadIdx.x >> 6;
    #pragma unroll
    for (int off = 32; off > 0; off >>= 1) v += __shfl_down(v, off);
    if (lane == 0) slots[wid] = v;
    __syncthreads();
    float r = slots[0] + slots[1];
    __syncthreads();
    return r;
}

// LN stats over 128 cols held in C-fragment layout (8 nt x f32x4)
__device__ __forceinline__ void lnC(const f32x4* vC, float* mu, float* inv) {
    float su[4] = {0, 0, 0, 0}, sq[4] = {0, 0, 0, 0};
    #pragma unroll
    for (int nt = 0; nt < 8; nt++)
        #pragma unroll
        for (int r = 0; r < 4; r++) { float v = vC[nt][r]; su[r] += v; sq[r] += v * v; }
    #pragma unroll
    for (int off = 1; off <= 8; off <<= 1)
        #pragma unroll
        for (int r = 0; r < 4; r++) { su[r] += __shfl_xor(su[r], off); sq[r] += __shfl_xor(sq[r], off); }
    #pragma unroll
    for (int r = 0; r < 4; r++) {
        mu[r] = su[r] * (1.f / HH);
        float var = (sq[r] - (float)HH * mu[r] * mu[r]) * (1.f / (HH - 1));
        inv[r] = 1.f / (sqrtf(var + EPSF) + EPSF);
    }
}

// ---------- device bodies ----------

__device__ void knn_body(int bid4, const float* __restrict__ X,
                         const float* __restrict__ mask,
                         int* __restrict__ E_idx,
                         float* __restrict__ D_nb) {
    int w = threadIdx.x >> 6, lane = threadIdx.x & 63;
    int g = bid4 * 4 + w;
    int b = g >> 11, n = g & 2047;
    const float* Xb = X + (size_t)b * NN * 3;
    const float* mb = mask + (size_t)b * NN;

    float xn0 = Xb[n * 3], xn1 = Xb[n * 3 + 1], xn2 = Xb[n * 3 + 2];
    float mn = mb[n];

    float Dv[32], m2a[32];
    float lmax = -1e30f;
    #pragma unroll
    for (int s = 0; s < 32; s++) {
        int j = s * 64 + lane;
        float dx = Xb[j * 3] - xn0, dy = Xb[j * 3 + 1] - xn1, dz = Xb[j * 3 + 2] - xn2;
        float d = sqrtf(dx * dx + dy * dy + dz * dz + EPSF);
        float m2 = mn * mb[j];
        float v = m2 * d;
        Dv[s] = v; m2a[s] = m2;
        lmax = fmaxf(lmax, v);
    }
    #pragma unroll
    for (int off = 1; off <= 32; off <<= 1) lmax = fmaxf(lmax, __shfl_xor(lmax, off));
    float Dmax = lmax;
    #pragma unroll
    for (int s = 0; s < 32; s++) Dv[s] += (1.f - m2a[s]) * Dmax;

    // per-lane top-2 (strict < keeps earliest slot on exact ties)
    float l1 = INFV, l2 = INFV; int s1 = 0, s2 = 0;
    #pragma unroll
    for (int s = 0; s < 32; s++) {
        float v = Dv[s];
        bool lt1 = v < l1;
        bool lt2 = v < l2;
        float o1 = l1; int os1 = s1;
        l1 = lt1 ? v : l1;  s1 = lt1 ? s : s1;
        l2 = lt1 ? o1 : (lt2 ? v : l2);
        s2 = lt1 ? os1 : (lt2 ? s : s2);
    }

    unsigned used = 0u;
    float keepd = 0.f; int keepj = 0;

    for (int s = 0; s < KK; s++) {
        float m = l1;
        #pragma unroll
        for (int off = 1; off <= 32; off <<= 1) m = fminf(m, __shfl_xor(m, off));
        unsigned long long ball = __ballot(l1 == m);
        int jwin;
        if (__popcll(ball) == 1) {
            int src = (int)(__ffsll((long long)ball) - 1);
            jwin = __shfl(s1 * 64 + lane, src);
        } else {
            int jme = (l1 == m) ? (s1 * 64 + lane) : 0x7FFFFFFF;
            jwin = jme;
            #pragma unroll
            for (int off = 1; off <= 32; off <<= 1) jwin = min(jwin, __shfl_xor(jwin, off));
        }
        if (lane == s) { keepd = m; keepj = jwin; }
        if (lane == (jwin & 63)) {
            used |= 1u << s1;
            l1 = l2; s1 = s2;
            l2 = INFV;
            if (l1 >= INFV) {   // rare refill
                l1 = INFV; l2 = INFV;
                #pragma unroll
                for (int i = 0; i < 32; i++) {
                    float v = ((used >> i) & 1u) ? INFV : Dv[i];
                    bool lt1 = v < l1;
                    bool lt2 = v < l2;
                    float o1 = l1; int os1 = s1;
                    l1 = lt1 ? v : l1;  s1 = lt1 ? i : s1;
                    l2 = lt1 ? o1 : (lt2 ? v : l2);
                    s2 = lt1 ? os1 : (lt2 ? i : s2);
                }
            }
        }
    }
    if (lane < KK) {
        E_idx[(size_t)g * KK + lane] = keepj;
        D_nb[(size_t)g * KK + lane] = keepd;
    }
}

__device__ __forceinline__ void packB(const float* __restrict__ src, short* __restrict__ dH,
                                      short* __restrict__ dL, int e, int KC, int N, int Kreal) {
    int j = e & 7, ln = (e >> 3) & 63, t = e >> 9;
    int kc = t % KC, nt = t / KC;
    int k = kc * 32 + (ln >> 4) * 8 + j;
    int n = nt * 16 + (ln & 15);
    float v = (k < Kreal) ? src[(size_t)k * N + n] : 0.f;
    short hi, lo; f2bf2(v, hi, lo);
    dH[e] = hi; dL[e] = lo;
}

__device__ void pack_body(int e,
                          const float* __restrict__ We, const float* __restrict__ Wq,
                          const float* __restrict__ lW1, const float* __restrict__ lW2,
                          const float* __restrict__ lW3, const float* __restrict__ lWi,
                          const float* __restrict__ lWo,
                          short* __restrict__ WeP, short* __restrict__ WqP,
                          short* __restrict__ W1bP, short* __restrict__ W2P,
                          short* __restrict__ W3P, short* __restrict__ WiP,
                          short* __restrict__ WoP, short* __restrict__ W1acP) {
    if (e < 8192) { packB(We, WeP, WeP + 8192, e, 2, 128, 39); return; }
    e -= 8192;
    if (e < 16384) { packB(Wq, WqP, WqP + 16384, e, 4, 128, 128); return; }
    e -= 16384;
    if (e < 49152) {
        int l = e >> 14, r = e & 16383;
        packB(lW1 + (size_t)l * 49152 + 16384, W1bP + l * 32768, W1bP + l * 32768 + 16384, r, 4, 128, 128);
        return;
    }
    e -= 49152;
    if (e < 49152) {
        int l = e >> 14, r = e & 16383;
        packB(lW2 + (size_t)l * 16384, W2P + l * 32768, W2P + l * 32768 + 16384, r, 4, 128, 128);
        return;
    }
    e -= 49152;
    if (e < 49152) {
        int l = e >> 14, r = e & 16383;
        packB(lW3 + (size_t)l * 16384, W3P + l * 32768, W3P + l * 32768 + 16384, r, 4, 128, 128);
        return;
    }
    e -= 49152;
    if (e < 196608) {
        int l = e / 65536, r = e % 65536;
        packB(lWi + (size_t)l * 65536, WiP + l * 131072, WiP + l * 131072 + 65536, r, 4, 512, 128);
        return;
    }
    e -= 196608;
    if (e < 196608) {
        int l = e / 65536, r = e % 65536;
        packB(lWo + (size_t)l * 65536, WoP + l * 131072, WoP + l * 131072 + 65536, r, 16, 128, 512);
        return;
    }
    e -= 196608;
    if (e < 98304) {
        int l = e / 32768, r = e % 32768;
        int j = r & 7, ln = (r >> 3) & 63, t = r >> 9;
        int kc = t & 3, nt = t >> 2;
        int k = kc * 32 + (ln >> 4) * 8 + j;
        int n = nt * 16 + (ln & 15);
        const float* base = lW1 + (size_t)l * 49152;
        float v = (n < 128) ? base[(size_t)k * 128 + n] : base[(size_t)(256 + k) * 128 + (n - 128)];
        short hi, lo; f2bf2(v, hi, lo);
        short* dH = W1acP + l * 65536;
        dH[r] = hi; dH[32768 + r] = lo;
    }
}

__device__ void orient_body(int t, const float* __restrict__ X,
                            float* __restrict__ AD, float* __restrict__ Of) {
    if (t >= BB * NN) return;
    int b = t / NN, n = t % NN;
    float* ad = AD + (size_t)t * 3;
    float* of = Of + (size_t)t * 9;
    if (n < 1 || n > NN - 3) {
        ad[0] = ad[1] = ad[2] = 0.f;
        #pragma unroll
        for (int i = 0; i < 9; i++) of[i] = 0.f;
        return;
    }
    const float* Xb = X + (size_t)b * NN * 3;
    float p0x = Xb[(n - 1) * 3], p0y = Xb[(n - 1) * 3 + 1], p0z = Xb[(n - 1) * 3 + 2];
    float p1x = Xb[n * 3],       p1y = Xb[n * 3 + 1],       p1z = Xb[n * 3 + 2];
    float p2x = Xb[(n + 1) * 3], p2y = Xb[(n + 1) * 3 + 1], p2z = Xb[(n + 1) * 3 + 2];
    float p3x = Xb[(n + 2) * 3], p3y = Xb[(n + 2) * 3 + 1], p3z = Xb[(n + 2) * 3 + 2];

    float u2x = p1x - p0x, u2y = p1y - p0y, u2z = p1z - p0z; norm3(u2x, u2y, u2z);
    float u1x = p2x - p1x, u1y = p2y - p1y, u1z = p2z - p1z; norm3(u1x, u1y, u1z);
    float u0x = p3x - p2x, u0y = p3y - p2y, u0z = p3z - p2z; norm3(u0x, u0y, u0z);

    float n2x = u2y * u1z - u2z * u1y, n2y = u2z * u1x - u2x * u1z, n2z = u2x * u1y - u2y * u1x;
    norm3(n2x, n2y, n2z);
    float n1x = u1y * u0z - u1z * u0y, n1y = u1z * u0x - u1x * u0z, n1z = u1x * u0y - u1y * u0x;
    norm3(n1x, n1y, n1z);

    float cosA = -(u1x * u0x + u1y * u0y + u1z * u0z);
    cosA = fminf(fmaxf(cosA, -1.f + EPSF), 1.f - EPSF);
    float A = acosf(cosA);
    float cosD = n2x * n1x + n2y * n1y + n2z * n1z;
    cosD = fminf(fmaxf(cosD, -1.f + EPSF), 1.f - EPSF);
    float sg = sgnf(u2x * n1x + u2y * n1y + u2z * n1z);
    float Dih = sg * acosf(cosD);

    ad[0] = cosf(A);
    ad[1] = sinf(A) * cosf(Dih);
    ad[2] = sinf(A) * sinf(Dih);

    float o1x = u2x - u1x, o1y = u2y - u1y, o1z = u2z - u1z; norm3(o1x, o1y, o1z);
    float cx = o1y * n2z - o1z * n2y, cy = o1z * n2x - o1x * n2z, cz = o1x * n2y - o1y * n2x;
    of[0] = o1x; of[1] = o1y; of[2] = o1z;
    of[3] = n2x; of[4] = n2y; of[5] = n2z;
    of[6] = cx;  of[7] = cy;  of[8] = cz;
}

// ---------- FRONT: knn (blocks 0..1023) | pack (1024..3615) | orient (3616..3631) ----------

__global__ __launch_bounds__(256) void front_kernel(const float* __restrict__ X,
                                                    const float* __restrict__ mask,
                                                    int* __restrict__ E_idx,
                                                    float* __restrict__ D_nb,
                                                    const float* __restrict__ We,
                                                    const float* __restrict__ Wq,
                                                    const float* __restrict__ lW1,
                                                    const float* __restrict__ lW2,
                                                    const float* __restrict__ lW3,
                                                    const float* __restrict__ lWi,
                                                    const float* __restrict__ lWo,
                                                    short* __restrict__ WeP,
                                                    short* __restrict__ WqP,
                                                    short* __restrict__ W1bP,
                                                    short* __restrict__ W2P,
                                                    short* __restrict__ W3P,
                                                    short* __restrict__ WiP,
                                                    short* __restrict__ WoP,
                                                    short* __restrict__ W1acP,
                                                    float* __restrict__ ADb,
                                                    float* __restrict__ Ofb) {
    int blk = blockIdx.x;
    if (blk < KNN_BLK) {
        knn_body(blk, X, mask, E_idx, D_nb);
    } else if (blk < KNN_BLK + PACK_BLK) {
        pack_body((blk - KNN_BLK) * 256 + threadIdx.x,
                  We, Wq, lW1, lW2, lW3, lWi, lWo,
                  WeP, WqP, W1bP, W2P, W3P, WiP, WoP, W1acP);
    } else {
        orient_body((blk - KNN_BLK - PACK_BLK) * 256 + threadIdx.x, X, ADb, Ofb);
    }
}

// ---------- MID: edge_feat (blocks 0..4095) | node_feat (4096..8191) ----------

__global__ __launch_bounds__(128) void mid_kernel(const float* __restrict__ X,
                                                  const int* __restrict__ E_idx,
                                                  const float* __restrict__ D_nb,
                                                  const float* __restrict__ Of,
                                                  const float* __restrict__ be,
                                                  const float* __restrict__ ge,
                                                  const float* __restrict__ he,
                                                  const float* __restrict__ bq,
                                                  const short* __restrict__ WeP,
                                                  const short* __restrict__ WqP,
                                                  unsigned short* __restrict__ hEbH,
                                                  const float* __restrict__ AD,
                                                  const float* __restrict__ Wn,
                                                  const float* __restrict__ bn,
                                                  const float* __restrict__ gn,
                                                  const float* __restrict__ hn,
                                                  const float* __restrict__ Wv,
                                                  const float* __restrict__ bv,
                                                  const float* __restrict__ W1_0,
                                                  const float* __restrict__ b1_0,
                                                  float* __restrict__ hV,
                                                  float* __restrict__ P,
                                                  float* __restrict__ Q) {
    __shared__ __align__(16) char smemRaw[15488];

    if (blockIdx.x < (unsigned)(BB * NN)) {
        // ----- edge_feat body -----
        short* AefH = (short*)smemRaw;                 // 32*72*2   = 4608 B
        short* AeH  = (short*)(smemRaw + 4608);        // 32*136*2  = 8704 B
        float* beS  = (float*)(smemRaw + 13312);       // 512 B
        float* geS  = beS + HH;
        float* heS  = geS + HH;
        float* bqS  = heS + HH;

        int bid = blockIdx.x; int b = bid >> 11, n = bid & 2047; int tid = threadIdx.x;
        int lane = tid & 63, w = tid >> 6;
        beS[tid] = be[tid]; geS[tid] = ge[tid]; heS[tid] = he[tid]; bqS[tid] = bq[tid];
        {
            unsigned* Az = (unsigned*)AefH;
            for (int i = tid; i < 32 * 72 / 2; i += 128) Az[i] = 0u;
        }
        __syncthreads();

        int part = tid >> 5, k = tid & 31;
        int e = E_idx[(size_t)bid * KK + k];
        float dpos = (float)e - (float)n;
        if (part == 1 || part == 2) {
            int p0 = (part - 1) * 4;
            #pragma unroll
            for (int p = 0; p < 4; p++) {
                float fr = expf((float)(2 * (p0 + p)) * -0.5756462732485115f);
                float ang = dpos * fr;
                AefH[k * 72 + p0 + p]     = (short)f2bf(__cosf(ang));
                AefH[k * 72 + 8 + p0 + p] = (short)f2bf(__sinf(ang));
            }
        } else if (part == 3) {
            float Dv = D_nb[(size_t)bid * KK + k];
            #pragma unroll
            for (int i = 0; i < 16; i++) {
                float m = (20.f / 15.f) * (float)i;
                float z = (Dv - m) * 0.8f;
                AefH[k * 72 + 16 + i] = (short)f2bf(__expf(-z * z));
            }
        } else {
            const float* Omp = Of + (size_t)(b * NN + n) * 9;
            const float* Onp = Of + (size_t)(b * NN + e) * 9;
            float Om[9], On[9];
            #pragma unroll
            for (int i = 0; i < 9; i++) { Om[i] = Omp[i]; On[i] = Onp[i]; }
            float vx = X[(size_t)(b * NN + e) * 3 + 0] - X[(size_t)(b * NN + n) * 3 + 0];
            float vy = X[(size_t)(b * NN + e) * 3 + 1] - X[(size_t)(b * NN + n) * 3 + 1];
            float vz = X[(size_t)(b * NN + e) * 3 + 2] - X[(size_t)(b * NN + n) * 3 + 2];
            float t0 = Om[0] * vx + Om[1] * vy + Om[2] * vz;
            float t1 = Om[3] * vx + Om[4] * vy + Om[5] * vz;
            float t2 = Om[6] * vx + Om[7] * vy + Om[8] * vz;
            float nr = fmaxf(sqrtf(t0 * t0 + t1 * t1 + t2 * t2), 1e-12f);
            AefH[k * 72 + 32] = (short)f2bf(t0 / nr);
            AefH[k * 72 + 33] = (short)f2bf(t1 / nr);
            AefH[k * 72 + 34] = (short)f2bf(t2 / nr);
            float R[9];
            #pragma unroll
            for (int i = 0; i < 3; i++)
                #pragma unroll
                for (int l = 0; l < 3; l++)
                    R[i * 3 + l] = Om[0 + i] * On[0 + l] + Om[3 + i] * On[3 + l] + Om[6 + i] * On[6 + l];
            float Rxx = R[0], Ryy = R[4], Rzz = R[8];
            float mx = 0.5f * sqrtf(fabsf(1.f + Rxx - Ryy - Rzz));
            float my = 0.5f * sqrtf(fabsf(1.f - Rxx + Ryy - Rzz));
            float mz = 0.5f * sqrtf(fabsf(1.f - Rxx - Ryy + Rzz));
            float qx = sgnf(R[7] - R[5]) * mx;
            float qy = sgnf(R[2] - R[6]) * my;
            float qz = sgnf(R[3] - R[1]) * mz;
            float qw = 0.5f * sqrtf(fmaxf(1.f + Rxx + Ryy + Rzz, 0.f));
            float qn = fmaxf(sqrtf(qx * qx + qy * qy + qz * qz + qw * qw), 1e-12f);
            AefH[k * 72 + 35] = (short)f2bf(qx / qn);
            AefH[k * 72 + 36] = (short)f2bf(qy / qn);
            AefH[k * 72 + 37] = (short)f2bf(qz / qn);
            AefH[k * 72 + 38] = (short)f2bf(qw / qn);
        }
        __syncthreads();

        int m = lane & 15, q = lane >> 4;
        int row = (w * 16 + m) * 72;
        short8 a0h = *(const short8*)&AefH[row + q * 8];
        short8 a1h = *(const short8*)&AefH[row + 32 + q * 8];
        f32x4 accA[8];
        #pragma unroll
        for (int nt = 0; nt < 8; nt++) {
            float bc = beS[nt * 16 + m];
            f32x4 acc = {bc, bc, bc, bc};
            const short* B0 = &WeP[((nt * 2 + 0) * 64 + lane) * 8];
            const short* B1 = &WeP[((nt * 2 + 1) * 64 + lane) * 8];
            short8 b0h = *(const short8*)B0, b0l = *(const short8*)(B0 + 8192);
            short8 b1h = *(const short8*)B1, b1l = *(const short8*)(B1 + 8192);
            acc = MFMA16(a0h, b0h, acc);
            acc = MFMA16(a0h, b0l, acc);
            acc = MFMA16(a1h, b1h, acc);
            acc = MFMA16(a1h, b1l, acc);
            accA[nt] = acc;
        }
        float mu[4], inv[4];
        lnC(accA, mu, inv);
        #pragma unroll
        for (int nt = 0; nt < 8; nt++) {
            int col = nt * 16 + m;
            float g = geS[col], hh = heS[col];
            #pragma unroll
            for (int r = 0; r < 4; r++) {
                int edge = w * 16 + q * 4 + r;
                float y = g * (accA[nt][r] - mu[r]) * inv[r] + hh;
                AeH[edge * 136 + col] = (short)f2bf(y);
            }
        }
        __syncthreads();

        short8 ah[4];
        #pragma unroll
        for (int kc = 0; kc < 4; kc++)
            ah[kc] = *(const short8*)&AeH[(w * 16 + m) * 136 + kc * 32 + q * 8];
        #pragma unroll
        for (int nt = 0; nt < 8; nt++) {
            int col = nt * 16 + m;
            float bc = bqS[col];
            f32x4 acc = {bc, bc, bc, bc};
            #pragma unroll
            for (int kc = 0; kc < 4; kc++) {
                const short* Bp = &WqP[((nt * 4 + kc) * 64 + lane) * 8];
                short8 bh = *(const short8*)Bp, bl = *(const short8*)(Bp + 16384);
                acc = MFMA16(ah[kc], bh, acc);
                acc = MFMA16(ah[kc], bl, acc);
            }
            #pragma unroll
            for (int r = 0; r < 4; r++) {
                int edge = w * 16 + q * 4 + r;
                hEbH[(size_t)bid * (KK * HH) + edge * HH + col] = f2bf(acc[r]);
            }
        }
    } else {
        // ----- node_feat body -----
        float* y     = (float*)smemRaw;                // 512 B (16-aligned)
        float* slots = (float*)(smemRaw + 512);

        int n = blockIdx.x - BB * NN; int h = threadIdx.x;
        float a0 = AD[n * 3], a1 = AD[n * 3 + 1], a2 = AD[n * 3 + 2];
        float v = bn[h] + a0 * Wn[h] + a1 * Wn[HH + h] + a2 * Wn[2 * HH + h];
        float mu = blk2sum(v, slots) * (1.f / HH);
        float d = v - mu;
        float var = blk2sum(d * d, slots) * (1.f / (HH - 1));
        float yv = gn[h] * d / (sqrtf(var + EPSF) + EPSF) + hn[h];
        y[h] = yv; __syncthreads();
        float acc = bv[h];
        for (int c4 = 0; c4 < 32; c4++) {
            f32x4 v4 = ((const f32x4*)y)[c4]; int c = 4 * c4;
            acc += v4.x * Wv[c * HH + h] + v4.y * Wv[(c + 1) * HH + h]
                 + v4.z * Wv[(c + 2) * HH + h] + v4.w * Wv[(c + 3) * HH + h];
        }
        hV[(size_t)n * HH + h] = acc;
        __syncthreads(); y[h] = acc; __syncthreads();
        float p = b1_0[h], qv = 0.f;
        for (int c4 = 0; c4 < 32; c4++) {
            f32x4 v4 = ((const f32x4*)y)[c4]; int c = 4 * c4;
            p  += v4.x * W1_0[c * HH + h]        + v4.y * W1_0[(c + 1) * HH + h]
                + v4.z * W1_0[(c + 2) * HH + h]  + v4.w * W1_0[(c + 3) * HH + h];
            qv += v4.x * W1_0[(256 + c) * HH + h]       + v4.y * W1_0[(256 + c + 1) * HH + h]
                + v4.z * W1_0[(256 + c + 2) * HH + h]   + v4.w * W1_0[(256 + c + 3) * HH + h];
        }
        P[(size_t)n * HH + h] = p;
        Q[(size_t)n * HH + h] = qv;
    }
}

// ---------- message kernel: one node per wave, all A-sides hi-only ----------

__global__ __launch_bounds__(128, 2) void msg_kernel(const float* __restrict__ mask,
                                                     const int* __restrict__ E_idx,
                                                     const unsigned short* __restrict__ hEbH,
                                                     const float* __restrict__ P,
                                                     const float* __restrict__ Q,
                                                     const short* __restrict__ W1bP,
                                                     const short* __restrict__ W2P,
                                                     const float* __restrict__ b2,
                                                     float* __restrict__ sOut,
                                                     float* __restrict__ cntOut) {
    __shared__ short AmH[2][32 * 136];

    int w = threadIdx.x >> 6, lane = threadIdx.x & 63;
    int g = blockIdx.x * 2 + w;          // node id
    int b = g >> 11;
    int m = lane & 15, q = lane >> 4;

    float maskv = mask[g];
    int erow[2][4]; float mt[2][4];
    #pragma unroll
    for (int t = 0; t < 2; t++)
        #pragma unroll
        for (int r = 0; r < 4; r++) {
            int row = t * 16 + q * 4 + r;
            erow[t][r] = E_idx[(size_t)g * KK + row];
            mt[t][r] = maskv * mask[b * NN + erow[t][r]];
        }
    {
        float c8 = mt[0][0] + mt[0][1] + mt[0][2] + mt[0][3]
                 + mt[1][0] + mt[1][1] + mt[1][2] + mt[1][3];
        c8 += __shfl_xor(c8, 16);
        c8 += __shfl_xor(c8, 32);
        if (lane == 0) cntOut[g] = c8;
    }

    float preg[8], b2reg[8];
    float qreg[8][2][4];
    #pragma unroll
    for (int nt = 0; nt < 8; nt++) {
        preg[nt]  = P[(size_t)g * HH + nt * 16 + m];
        b2reg[nt] = b2[nt * 16 + m];
        #pragma unroll
        for (int t = 0; t < 2; t++)
            #pragma unroll
            for (int r = 0; r < 4; r++)
                qreg[nt][t][r] = Q[((size_t)b * NN + erow[t][r]) * HH + nt * 16 + m];
    }

    // phase 1: m1 = relu(P + Q[nbr] + h_E @ W1b)
    {
        const unsigned short* hbH = hEbH + (size_t)g * (KK * HH);
        short8 aheH[2][4];
        #pragma unroll
        for (int t = 0; t < 2; t++)
            #pragma unroll
            for (int kc = 0; kc < 4; kc++)
                aheH[t][kc] = *(const short8*)(hbH + (t * 16 + m) * HH + kc * 32 + q * 8);
        #pragma unroll
        for (int nt = 0; nt < 8; nt++) {
            f32x4 t0 = {0.f, 0.f, 0.f, 0.f}, t1 = {0.f, 0.f, 0.f, 0.f};
            #pragma unroll
            for (int kc = 0; kc < 4; kc++) {
                const short* Bp = &W1bP[((nt * 4 + kc) * 64 + lane) * 8];
                short8 bh = *(const short8*)Bp, bl = *(const short8*)(Bp + 16384);
                t0 = MFMA16(aheH[0][kc], bh, t0);
                t0 = MFMA16(aheH[0][kc], bl, t0);
                t1 = MFMA16(aheH[1][kc], bh, t1);
                t1 = MFMA16(aheH[1][kc], bl, t1);
            }
            int col = nt * 16 + m;
            float pp = preg[nt];
            #pragma unroll
            for (int r = 0; r < 4; r++) {
                float v0 = fmaxf(t0[r] + pp + qreg[nt][0][r], 0.f);
                AmH[w][(q * 4 + r) * 136 + col] = (short)f2bf(v0);
                float v1 = fmaxf(t1[r] + pp + qreg[nt][1][r], 0.f);
                AmH[w][(16 + q * 4 + r) * 136 + col] = (short)f2bf(v1);
            }
        }
    }
    __syncthreads();

    // phase 2: m2 = relu(m1 @ W2 + b2); masked sum over 32 edges
    {
        short8 amh[2][4];
        #pragma unroll
        for (int t = 0; t < 2; t++)
            #pragma unroll
            for (int kc = 0; kc < 4; kc++)
                amh[t][kc] = *(const short8*)&AmH[w][(t * 16 + m) * 136 + kc * 32 + q * 8];
        #pragma unroll
        for (int nt = 0; nt < 8; nt++) {
            float bc = b2reg[nt];
            f32x4 a0 = {bc, bc, bc, bc}, a1 = {bc, bc, bc, bc};
            #pragma unroll
            for (int kc = 0; kc < 4; kc++) {
                const short* Bp = &W2P[((nt * 4 + kc) * 64 + lane) * 8];
                short8 bh = *(const short8*)Bp, bl = *(const short8*)(Bp + 16384);
                a0 = MFMA16(amh[0][kc], bh, a0);
                a0 = MFMA16(amh[0][kc], bl, a0);
                a1 = MFMA16(amh[1][kc], bh, a1);
                a1 = MFMA16(amh[1][kc], bl, a1);
            }
            float part = 0.f;
            #pragma unroll
            for (int r = 0; r < 4; r++)
                part += fmaxf(a0[r], 0.f) * mt[0][r] + fmaxf(a1[r], 0.f) * mt[1][r];
            part += __shfl_xor(part, 16);
            part += __shfl_xor(part, 32);
            if (q == 0) sOut[(size_t)g * HH + nt * 16 + m] = part;
        }
    }
}

// ---------- node kernel: 4 waves, A-sides hi-only ----------

#define HSTR 520   // LDS stride (shorts) for 512-wide hidden staging

__global__ __launch_bounds__(256, 3) void node_kernel(const float* __restrict__ mask,
                                                      const float* __restrict__ sbuf,
                                                      const float* __restrict__ cntb,
                                                      const float* __restrict__ hVin,
                                                      const short* __restrict__ W3P,
                                                      const float* __restrict__ b3,
                                                      const short* __restrict__ WiP,
                                                      const float* __restrict__ biN,
                                                      const short* __restrict__ WoP,
                                                      const float* __restrict__ boN,
                                                      const float* __restrict__ g0,
                                                      const float* __restrict__ h0,
                                                      const float* __restrict__ g1,
                                                      const float* __restrict__ h1,
                                                      const short* __restrict__ W1P,
                                                      const float* __restrict__ b1n,
                                                      float* __restrict__ hVout,
                                                      float* __restrict__ Pn,
                                                      float* __restrict__ Qn) {
    __shared__ short rbH[16 * 136];
    __shared__ short hbH[16 * HSTR];
    __shared__ float redS[4][2][16];
    __shared__ float g0S[128], h0S[128], g1S[128], h1S[128], b3S[128], boS[128], b1S[128];
    __shared__ float biS[512];

    int tid = threadIdx.x;
    int w = tid >> 6, lane = tid & 63;
    int m = lane & 15, q = lane >> 4;
    int rowT = blockIdx.x * 16;

    for (int i = tid; i < 128; i += 256) {
        g0S[i] = g0[i]; h0S[i] = h0[i]; g1S[i] = g1[i]; h1S[i] = h1[i];
        b3S[i] = b3[i]; boS[i] = boN[i]; b1S[i] = W1P ? b1n[i] : 0.f;
    }
    for (int i = tid; i < 512; i += 256) biS[i] = biN[i];
    __syncthreads();

    short8 ash[4];
    #pragma unroll
    for (int kc = 0; kc < 4; kc++) {
        const float* sp = &sbuf[(size_t)(rowT + m) * HH + kc * 32 + q * 8];
        f32x4 x0 = *(const f32x4*)sp;
        f32x4 x1 = *(const f32x4*)(sp + 4);
        ash[kc] = cvt8h(x0, x1);
    }
    float cntr[4];
    #pragma unroll
    for (int r = 0; r < 4; r++) cntr[r] = cntb[rowT + q * 4 + r];

    f32x4 vC2[2];
    #pragma unroll
    for (int t = 0; t < 2; t++) {
        int nt = 2 * w + t;
        f32x4 a = {0.f, 0.f, 0.f, 0.f};
        #pragma unroll
        for (int kc = 0; kc < 4; kc++) {
            const short* Bp = &W3P[((nt * 4 + kc) * 64 + lane) * 8];
            short8 bh = *(const short8*)Bp, bl = *(const short8*)(Bp + 16384);
            a = MFMA16(ash[kc], bh, a);
            a = MFMA16(ash[kc], bl, a);
        }
        int col = nt * 16 + m;
        #pragma unroll
        for (int r = 0; r < 4; r++) {
            float tv = (a[r] + cntr[r] * b3S[col]) * (1.f / 30.f);
            a[r] = hVin[(size_t)(rowT + q * 4 + r) * HH + col] + tv;
        }
        vC2[t] = a;
    }

    // LN0 (cross-wave)
    {
        float su[4] = {0, 0, 0, 0}, sq[4] = {0, 0, 0, 0};
        #pragma unroll
        for (int t = 0; t < 2; t++)
            #pragma unroll
            for (int r = 0; r < 4; r++) { float v = vC2[t][r]; su[r] += v; sq[r] += v * v; }
        #pragma unroll
        for (int off = 1; off <= 8; off <<= 1)
            #pragma unroll
            for (int r = 0; r < 4; r++) { su[r] += __shfl_xor(su[r], off); sq[r] += __shfl_xor(sq[r], off); }
        if (m == 0) {
            #pragma unroll
            for (int r = 0; r < 4; r++) { redS[w][0][q * 4 + r] = su[r]; redS[w][1][q * 4 + r] = sq[r]; }
        }
    }
    __syncthreads();
    float mu[4], inv[4];
    #pragma unroll
    for (int r = 0; r < 4; r++) {
        int row = q * 4 + r;
        float S  = redS[0][0][row] + redS[1][0][row] + redS[2][0][row] + redS[3][0][row];
        float Q2 = redS[0][1][row] + redS[1][1][row] + redS[2][1][row] + redS[3][1][row];
        mu[r] = S * (1.f / HH);
        float var = (Q2 - (float)HH * mu[r] * mu[r]) * (1.f / (HH - 1));
        inv[r] = 1.f / (sqrtf(var + EPSF) + EPSF);
    }
    #pragma unroll
    for (int t = 0; t < 2; t++) {
        int col = (2 * w + t) * 16 + m;
        #pragma unroll
        for (int r = 0; r < 4; r++)
            vC2[t][r] = g0S[col] * (vC2[t][r] - mu[r]) * inv[r] + h0S[col];
    }
    #pragma unroll
    for (int t = 0; t < 2; t++) {
        int col = (2 * w + t) * 16 + m;
        #pragma unroll
        for (int r = 0; r < 4; r++)
            rbH[(q * 4 + r) * 136 + col] = (short)f2bf(vC2[t][r]);
    }
    __syncthreads();

    short8 avh[4];
    #pragma unroll
    for (int kc = 0; kc < 4; kc++)
        avh[kc] = *(const short8*)&rbH[m * 136 + kc * 32 + q * 8];

    // FFN-in: wave's 128 hidden cols
    #pragma unroll
    for (int nt2 = 0; nt2 < 8; nt2++) {
        int jcol = w * 128 + nt2 * 16 + m;
        float bb = biS[jcol];
        f32x4 a = {bb, bb, bb, bb};
        #pragma unroll
        for (int kc = 0; kc < 4; kc++) {
            const short* Bp = &WiP[(((w * 8 + nt2) * 4 + kc) * 64 + lane) * 8];
            short8 bh = *(const short8*)Bp, bl = *(const short8*)(Bp + 65536);
            a = MFMA16(avh[kc], bh, a);
            a = MFMA16(avh[kc], bl, a);
        }
        #pragma unroll
        for (int r = 0; r < 4; r++)
            hbH[(q * 4 + r) * HSTR + jcol] = (short)f2bf(fmaxf(a[r], 0.f));
    }
    __syncthreads();

    // FFN-out: wave's 2 col-tiles over ALL 512 hidden
    f32x4 oC2[2] = {{0.f, 0.f, 0.f, 0.f}, {0.f, 0.f, 0.f, 0.f}};
    for (int kc2 = 0; kc2 < 16; kc2++) {
        short8 ahh = *(const short8*)&hbH[m * HSTR + kc2 * 32 + q * 8];
        #pragma unroll
        for (int t = 0; t < 2; t++) {
            int nt = 2 * w + t;
            const short* Bp = &WoP[((nt * 16 + kc2) * 64 + lane) * 8];
            short8 bh = *(const short8*)Bp, bl = *(const short8*)(Bp + 65536);
            oC2[t] = MFMA16(ahh, bh, oC2[t]);
            oC2[t] = MFMA16(ahh, bl, oC2[t]);
        }
    }
    #pragma unroll
    for (int t = 0; t < 2; t++) {
        int col = (2 * w + t) * 16 + m;
        #pragma unroll
        for (int r = 0; r < 4; r++)
            oC2[t][r] += boS[col] + vC2[t][r];
    }

    // LN1 (cross-wave)
    {
        float su[4] = {0, 0, 0, 0}, sq[4] = {0, 0, 0, 0};
        #pragma unroll
        for (int t = 0; t < 2; t++)
            #pragma unroll
            for (int r = 0; r < 4; r++) { float v = oC2[t][r]; su[r] += v; sq[r] += v * v; }
        #pragma unroll
        for (int off = 1; off <= 8; off <<= 1)
            #pragma unroll
            for (int r = 0; r < 4; r++) { su[r] += __shfl_xor(su[r], off); sq[r] += __shfl_xor(sq[r], off); }
        __syncthreads();   // redS reuse
        if (m == 0) {
            #pragma unroll
            for (int r = 0; r < 4; r++) { redS[w][0][q * 4 + r] = su[r]; redS[w][1][q * 4 + r] = sq[r]; }
        }
    }
    __syncthreads();
    #pragma unroll
    for (int r = 0; r < 4; r++) {
        int row = q * 4 + r;
        float S  = redS[0][0][row] + redS[1][0][row] + redS[2][0][row] + redS[3][0][row];
        float Q2 = redS[0][1][row] + redS[1][1][row] + redS[2][1][row] + redS[3][1][row];
        mu[r] = S * (1.f / HH);
        float var = (Q2 - (float)HH * mu[r] * mu[r]) * (1.f / (HH - 1));
        inv[r] = 1.f / (sqrtf(var + EPSF) + EPSF);
    }
    float mk[4];
    #pragma unroll
    for (int r = 0; r < 4; r++) mk[r] = mask[rowT + q * 4 + r];
    #pragma unroll
    for (int t = 0; t < 2; t++) {
        int col = (2 * w + t) * 16 + m;
        #pragma unroll
        for (int r = 0; r < 4; r++) {
            float y = g1S[col] * (oC2[t][r] - mu[r]) * inv[r] + h1S[col];
            y *= mk[r];
            oC2[t][r] = y;
            hVout[(size_t)(rowT + q * 4 + r) * HH + col] = y;
        }
    }

    // fused next-layer premix (wave's 4 of 16 col-tiles)
    if (W1P) {
        __syncthreads();
        #pragma unroll
        for (int t = 0; t < 2; t++) {
            int col = (2 * w + t) * 16 + m;
            #pragma unroll
            for (int r = 0; r < 4; r++)
                rbH[(q * 4 + r) * 136 + col] = (short)f2bf(oC2[t][r]);
        }
        __syncthreads();
        short8 ayh[4];
        #pragma unroll
        for (int kc = 0; kc < 4; kc++)
            ayh[kc] = *(const short8*)&rbH[m * 136 + kc * 32 + q * 8];
        #pragma unroll
        for (int u = 0; u < 4; u++) {
            int nt = w * 4 + u;
            int col = nt * 16 + m;
            float b0 = (nt < 8) ? b1S[col] : 0.f;
            f32x4 a = {b0, b0, b0, b0};
            #pragma unroll
            for (int kc = 0; kc < 4; kc++) {
                const short* Bp = &W1P[((nt * 4 + kc) * 64 + lane) * 8];
                short8 bh = *(const short8*)Bp, bl = *(const short8*)(Bp + 32768);
                a = MFMA16(ayh[kc], bh, a);
                a = MFMA16(ayh[kc], bl, a);
            }
            #pragma unroll
            for (int r = 0; r < 4; r++) {
                size_t row = rowT + q * 4 + r;
                if (nt < 8) Pn[row * HH + col] = a[r];
                else        Qn[row * HH + (col - 128)] = a[r];
            }
        }
    }
}

// ---------- launch ----------

extern "C" void kernel_launch(void* const* d_in, const int* in_sizes, int n_in,
                              void* d_out, int out_size, void* d_ws, size_t ws_size,
                              hipStream_t stream) {
    const float* X    = (const float*)d_in[0];
    const float* mask = (const float*)d_in[1];
    const float* Wn   = (const float*)d_in[2];
    const float* bn   = (const float*)d_in[3];
    const float* gn   = (const float*)d_in[4];
    const float* hn   = (const float*)d_in[5];
    const float* We   = (const float*)d_in[6];
    const float* be   = (const float*)d_in[7];
    const float* ge   = (const float*)d_in[8];
    const float* he   = (const float*)d_in[9];
    const float* Wv   = (const float*)d_in[10];
    const float* bv   = (const float*)d_in[11];
    const float* Wq   = (const float*)d_in[12];
    const float* bq   = (const float*)d_in[13];
    const float* lW1  = (const float*)d_in[14];
    const float* lb1  = (const float*)d_in[15];
    const float* lW2  = (const float*)d_in[16];
    const float* lb2  = (const float*)d_in[17];
    const float* lW3  = (const float*)d_in[18];
    const float* lb3  = (const float*)d_in[19];
    const float* lWi  = (const float*)d_in[20];
    const float* lbi  = (const float*)d_in[21];
    const float* lWo  = (const float*)d_in[22];
    const float* lbo  = (const float*)d_in[23];
    const float* lg0  = (const float*)d_in[24];
    const float* lh0  = (const float*)d_in[25];
    const float* lg1  = (const float*)d_in[26];
    const float* lh1  = (const float*)d_in[27];

    char* ws = (char*)d_ws;
    size_t off = 0;
    auto alloc = [&](size_t nbytes) { void* p = ws + off; off += (nbytes + 15) & ~(size_t)15; return p; };
    int*   E_idx = (int*)  alloc((size_t)BB * NN * KK * 4);
    float* D_nb  = (float*)alloc((size_t)BB * NN * KK * 4);
    float* ADb   = (float*)alloc((size_t)BB * NN * 3 * 4);
    float* Ofb   = (float*)alloc((size_t)BB * NN * 9 * 4);
    float* hV    = (float*)alloc((size_t)BB * NN * HH * 4);
    unsigned short* hEbH = (unsigned short*)alloc((size_t)BB * NN * KK * HH * 2);
    float* Pb    = (float*)alloc((size_t)BB * NN * HH * 4);
    float* Qb    = (float*)alloc((size_t)BB * NN * HH * 4);
    float* sBuf  = (float*)alloc((size_t)BB * NN * HH * 4);
    float* cntB  = (float*)alloc((size_t)BB * NN * 4);
    short* WeP   = (short*)alloc(2 * 8192 * 2);
    short* WqP   = (short*)alloc(2 * 16384 * 2);
    short* W1bP  = (short*)alloc(3 * 2 * 16384 * 2);
    short* W2P   = (short*)alloc(3 * 2 * 16384 * 2);
    short* W3P   = (short*)alloc(3 * 2 * 16384 * 2);
    short* WiP   = (short*)alloc(3 * 2 * 65536 * 2);
    short* WoP   = (short*)alloc(3 * 2 * 65536 * 2);
    short* W1acP = (short*)alloc(3 * 2 * 32768 * 2);
    if (off > ws_size) return;

    // Dispatch 1: knn | pack | orient (mutually independent)
    front_kernel<<<KNN_BLK + PACK_BLK + ORIENT_BLK, 256, 0, stream>>>(
        X, mask, E_idx, D_nb,
        We, Wq, lW1, lW2, lW3, lWi, lWo,
        WeP, WqP, W1bP, W2P, W3P, WiP, WoP, W1acP,
        ADb, Ofb);

    // Dispatch 2: edge_feat | node_feat (mutually independent; both need dispatch 1)
    mid_kernel<<<2 * BB * NN, 128, 0, stream>>>(
        X, E_idx, D_nb, Ofb, be, ge, he, bq, WeP, WqP, hEbH,
        ADb, Wn, bn, gn, hn, Wv, bv, lW1, lb1, hV, Pb, Qb);

    for (int l = 0; l < 3; l++) {
        int last = (l == 2);
        msg_kernel<<<BB * NN / 2, HH, 0, stream>>>(
            mask, E_idx, hEbH, Pb, Qb,
            W1bP + (size_t)l * 32768,
            W2P + (size_t)l * 32768, lb2 + (size_t)l * HH,
            sBuf, cntB);
        node_kernel<<<BB * NN / 16, 256, 0, stream>>>(
            mask, sBuf, cntB, hV,
            W3P + (size_t)l * 32768, lb3 + (size_t)l * HH,
            WiP + (size_t)l * 131072, lbi + (size_t)l * DFF,
            WoP + (size_t)l * 131072, lbo + (size_t)l * HH,
            lg0 + (size_t)l * HH, lh0 + (size_t)l * HH,
            lg1 + (size_t)l * HH, lh1 + (size_t)l * HH,
            last ? nullptr : (W1acP + (size_t)(l + 1) * 65536),
            last ? nullptr : (lb1 + (size_t)(l + 1) * HH),
            last ? (float*)d_out : hV,
            Pb, Qb);
    }
}